// Round 16
// baseline (401.946 us; speedup 1.0000x reference)
//
#include <hip/hip_runtime.h>
#include <hip/hip_bf16.h>
#include <stdint.h>

typedef __attribute__((ext_vector_type(8)))  short short8;
typedef __attribute__((ext_vector_type(4)))  float floatx4;
typedef __attribute__((ext_vector_type(16))) float floatx16;

#define S_LEN 2048
#define DH    128
#define BQ    64
#define BKV   64
#define NSTEP (S_LEN / BKV)
#define SCALE 0.08838834764831845f                  // 1/sqrt(128)
#define SCALE2 0.12753785429791905f                 // SCALE * log2(e)
#define DTHR 11.541560327111708f                    // 8 * log2(e)

__device__ __forceinline__ float ex2(float x) { return __builtin_amdgcn_exp2f(x); }

__device__ __forceinline__ unsigned short f2b(float f) {
    union { float f; unsigned u; } v; v.f = f;
    unsigned r = v.u + 0x7fffu + ((v.u >> 16) & 1u);
    return (unsigned short)(r >> 16);
}

__device__ __forceinline__ unsigned cvt_pk(float lo, float hi) {
    unsigned r;
    asm("v_cvt_pk_bf16_f32 %0, %1, %2" : "=v"(r) : "v"(lo), "v"(hi));
    return r;
}

// ============================ prepass kernels ============================

// K fragment-major (verified R13-R15): frag F=(wk,dsub,hi,lq) of tile (b,T)
// holds K[b][kv=T*64+wk*32+lq][d=dsub*16+hi*8 .. +8] as 8 bf16.
__global__ __launch_bounds__(256) void kfrag_make(const float* __restrict__ K,
                                                  unsigned short* __restrict__ KF)
{
    const int T = blockIdx.x, b = blockIdx.y;
    const float* Kb = K + ((size_t)b * S_LEN + T * 64) * DH;
    unsigned short* out = KF + ((size_t)(b * 32 + T)) * 1024 * 8;
    #pragma unroll
    for (int i = 0; i < 4; ++i) {
        int F = i * 256 + threadIdx.x;
        int lq = F & 31, h = (F >> 5) & 1, dsub = (F >> 6) & 7, wk = F >> 9;
        const float* src = Kb + (size_t)(wk * 32 + lq) * DH + dsub * 16 + h * 8;
        float4 a = *(const float4*)src, bb = *(const float4*)(src + 4);
        short8 f;
        f[0] = f2b(a.x);  f[1] = f2b(a.y);  f[2] = f2b(a.z);  f[3] = f2b(a.w);
        f[4] = f2b(bb.x); f[5] = f2b(bb.y); f[6] = f2b(bb.z); f[7] = f2b(bb.w);
        *(short8*)(out + (size_t)F * 8) = f;
    }
}

// V fragment-major (verified R13-R15): frag (b,T,ds,wk,ks,hi,lq) holds
// V[b][kv=T*64+wk*32+ks*16+hi*8+e][d=ds*32+lq] transposed.
__global__ __launch_bounds__(256) void vfrag_make(const float* __restrict__ V,
                                                  unsigned short* __restrict__ VF)
{
    __shared__ float t[32][33];
    const int k0 = blockIdx.x * 32, d0 = blockIdx.y * 32, b = blockIdx.z;
    const int tx = threadIdx.x & 31, ty = threadIdx.x >> 5;
    const float* Vb = V + ((size_t)b * S_LEN + k0) * DH + d0;
    #pragma unroll
    for (int i = 0; i < 4; ++i)
        t[ty + 8 * i][tx] = Vb[(size_t)(ty + 8 * i) * DH + tx];
    __syncthreads();
    if (threadIdx.x < 128) {
        const int lq = threadIdx.x & 31;
        const int h  = (threadIdx.x >> 5) & 1;
        const int ks = threadIdx.x >> 6;
        const int T = k0 >> 6, wk = (k0 >> 5) & 1, ds = d0 >> 5;
        short8 f;
        #pragma unroll
        for (int e = 0; e < 8; ++e)
            f[e] = f2b(t[ks * 16 + h * 8 + e][lq]);
        unsigned short* o = VF +
            ((((((size_t)(b * 32 + T) * 4 + ds) * 2 + wk) * 2 + ks) * 2 + h) * 32 + lq) * 8;
        *(short8*)o = f;
    }
}

// ============================ main kernel ============================
// Fragment-major K/V from global (L2), K ping-pong one step ahead; mask
// ballot-packed in-kernel 2 groups ahead (per-row contiguous int4 loads,
// 4-deep LDS ring); one raw s_barrier per group (no vmcnt drain). 3 blocks/CU.
// 32x32 MFMA; waves (wq,wk); in-reg P exchange; per-wave (m,l); end merge.
// LDS: merge 0..34816; packed-mask ring 34816..45056 (4 bufs x 64 rows x 40B)
#define PM_OFF 34816
#define LDS_BYTES 45056

__global__ __launch_bounds__(256, 3)
void attn_fwd(const float* __restrict__ Q, const unsigned short* __restrict__ KF,
              const unsigned short* __restrict__ VF,
              const int* __restrict__ M,
              float* __restrict__ O)
{
    __shared__ __align__(128) char lds[LDS_BYTES];

    const int tid  = threadIdx.x;
    const int lane = tid & 63;
    const int w    = tid >> 6;
    const int wq   = w & 1;
    const int wk   = w >> 1;
    const int lq   = lane & 31;
    const int hi   = lane >> 5;
    const int qt   = blockIdx.x;
    const int b    = blockIdx.y;
    const int q0   = qt * BQ;

    // ---- Q B-fragments (scale*log2e folded)
    short8 qf[8];
    {
        const float* qrow = Q + ((size_t)(b * S_LEN + q0 + wq * 32 + lq)) * DH;
        #pragma unroll
        for (int dsub = 0; dsub < 8; ++dsub) {
            const float* p = qrow + dsub * 16 + hi * 8;
            float4 a  = *(const float4*)(p);
            float4 bb = *(const float4*)(p + 4);
            short8 f;
            f[0] = f2b(a.x * SCALE2);  f[1] = f2b(a.y * SCALE2);
            f[2] = f2b(a.z * SCALE2);  f[3] = f2b(a.w * SCALE2);
            f[4] = f2b(bb.x * SCALE2); f[5] = f2b(bb.y * SCALE2);
            f[6] = f2b(bb.z * SCALE2); f[7] = f2b(bb.w * SCALE2);
            qf[dsub] = f;
        }
    }

    float m_run = -1e30f;
    float l_run = 0.f;
    floatx16 accO[4];
    #pragma unroll
    for (int i = 0; i < 4; ++i) accO[i] = (floatx16)(0.f);

    const unsigned short* KFl = KF + (((size_t)(b * 32) * 2 + wk) * 512
                                      + (size_t)hi * 32 + lq) * 8;
    const unsigned short* VFl = VF + ((((size_t)(b * 32) * 4 * 2 + wk) * 2) * 2 * 32
                                      + (size_t)hi * 32 + lq) * 8;

    const int* Mq = M + (size_t)b * S_LEN * S_LEN + (size_t)q0 * S_LEN;

    int4 mA[4], mB[4];
    short8 kfA[8], kfB[8], vfc[8];
    unsigned long long mgc[4];

#define LOAD_KF(DST, T) {                                                     \
    const unsigned short* kp_ = KFl + (size_t)(T) * (2 * 512 * 8);            \
    _Pragma("unroll")                                                         \
    for (int dsub = 0; dsub < 8; ++dsub)                                      \
        DST[dsub] = *(const short8*)(kp_ + dsub * 512);                       \
}

#define LOAD_VF(T) {                                                          \
    _Pragma("unroll")                                                         \
    for (int ds = 0; ds < 4; ++ds)                                            \
        _Pragma("unroll")                                                     \
        for (int ks = 0; ks < 2; ++ks)                                        \
            vfc[ds * 2 + ks] = *(const short8*)(VFl                           \
                + ((size_t)(T) * 16 + ds * 4 + ks) * (2 * 32 * 8));           \
}

#define LOAD_MROWS(DST, G, SB) {                                              \
    _Pragma("unroll")                                                         \
    for (int rr = 0; rr < 4; ++rr)                                            \
        DST[rr] = *(const int4*)(Mq + (size_t)(w * 16 + (SB) * 4 + rr) * S_LEN \
                                 + (G) * 256 + 4 * lane);                     \
}
#define PACK_MROWS(SRC, PBUF, SB) {                                           \
    char* pms_ = lds + PM_OFF + (PBUF) * 2560;                                \
    _Pragma("unroll")                                                         \
    for (int rr = 0; rr < 4; ++rr) {                                          \
        int4 mm = SRC[rr];                                                    \
        unsigned long long b0 = __ballot(mm.x != 0);                          \
        unsigned long long b1 = __ballot(mm.y != 0);                          \
        unsigned long long b2 = __ballot(mm.z != 0);                          \
        unsigned long long b3 = __ballot(mm.w != 0);                          \
        if (lane == 0) {                                                      \
            char* rp_ = pms_ + (w * 16 + (SB) * 4 + rr) * 40;                 \
            *(unsigned long long*)(rp_ +  0) = b0;                            \
            *(unsigned long long*)(rp_ +  8) = b1;                            \
            *(unsigned long long*)(rp_ + 16) = b2;                            \
            *(unsigned long long*)(rp_ + 24) = b3;                            \
        }                                                                     \
    }                                                                         \
}

    // ---- prologue: pack groups 0 and 1; K(0) into kfA
    LOAD_KF(kfA, 0);
    #pragma unroll
    for (int gg = 0; gg < 2; ++gg)
        #pragma unroll
        for (int sb = 0; sb < 4; ++sb) {
            int4 t_[4];
            LOAD_MROWS(t_, gg, sb)
            PACK_MROWS(t_, gg, sb)
        }
    __syncthreads();

#define STEP_BODY(T, TT, KFC, KFN, MNEW, MOLD) {                              \
    if ((T) + 1 < NSTEP) LOAD_KF(KFN, (T) + 1);                               \
    LOAD_VF(T);                                                               \
    if ((T) < 24) LOAD_MROWS(MNEW, ((T) >> 2) + 2, TT)                        \
    if ((T) >= 1 && (T) <= 24) {                                              \
        const int ps_   = ((T) - 1) & 3;                                      \
        const int pbuf_ = (((((T) - 1) >> 2) + 2) & 3);                       \
        PACK_MROWS(MOLD, pbuf_, ps_)                                          \
    }                                                                         \
    if ((TT) == 0) {                                                          \
        const char* pmb_ = lds + PM_OFF + (((T) >> 2) & 3) * 2560             \
                           + (wq * 32 + lq) * 40;                             \
        mgc[0] = *(const unsigned long long*)(pmb_ + 0);                      \
        mgc[1] = *(const unsigned long long*)(pmb_ + 8);                      \
        mgc[2] = *(const unsigned long long*)(pmb_ + 16);                     \
        mgc[3] = *(const unsigned long long*)(pmb_ + 24);                     \
    }                                                                         \
    /* QK^T from KFC (loaded one full step ago) */                            \
    floatx16 accS = (floatx16)(0.f);                                          \
    __builtin_amdgcn_s_setprio(1);                                            \
    _Pragma("unroll")                                                         \
    for (int dsub = 0; dsub < 8; ++dsub)                                      \
        accS = __builtin_amdgcn_mfma_f32_32x32x16_bf16(                       \
                   KFC[dsub], qf[dsub], accS, 0, 0, 0);                       \
    __builtin_amdgcn_s_setprio(0);                                            \
    const int base_ = (TT) * 16 + wk * 8 + hi;                                \
    unsigned mb0 = (unsigned)(mgc[0] >> base_);                               \
    unsigned mb1 = (unsigned)(mgc[1] >> base_);                               \
    unsigned mb2 = (unsigned)(mgc[2] >> base_);                               \
    unsigned mb3 = (unsigned)(mgc[3] >> base_);                               \
    float p_[16];                                                             \
    _Pragma("unroll")                                                         \
    for (int j = 0; j < 4; ++j) {                                             \
        p_[4*j+0] = ((mb0 >> (2*j)) & 1u) ? -1e30f : accS[4*j+0];             \
        p_[4*j+1] = ((mb1 >> (2*j)) & 1u) ? -1e30f : accS[4*j+1];             \
        p_[4*j+2] = ((mb2 >> (2*j)) & 1u) ? -1e30f : accS[4*j+2];             \
        p_[4*j+3] = ((mb3 >> (2*j)) & 1u) ? -1e30f : accS[4*j+3];             \
    }                                                                         \
    float mx = p_[0];                                                         \
    _Pragma("unroll")                                                         \
    for (int r = 1; r < 16; ++r) mx = fmaxf(mx, p_[r]);                       \
    mx = fmaxf(mx, __shfl_xor(mx, 32));                                       \
    int need = __any(mx - m_run > DTHR);                                      \
    float corr = 1.0f;                                                        \
    if (need) {                                                               \
        float mn = fmaxf(m_run, mx);                                          \
        corr = ex2(m_run - mn);                                               \
        m_run = mn;                                                           \
    }                                                                         \
    float ts = 0.f;                                                           \
    _Pragma("unroll")                                                         \
    for (int r = 0; r < 16; ++r) { p_[r] = ex2(p_[r] - m_run); ts += p_[r]; } \
    ts += __shfl_xor(ts, 32);                                                 \
    if (need) {                                                               \
        l_run = l_run * corr + ts;                                            \
        _Pragma("unroll")                                                     \
        for (int ds = 0; ds < 4; ++ds) {                                      \
            floatx16 o = accO[ds];                                            \
            _Pragma("unroll")                                                 \
            for (int r = 0; r < 16; ++r) o[r] *= corr;                        \
            accO[ds] = o;                                                     \
        }                                                                     \
    } else {                                                                  \
        l_run += ts;                                                          \
    }                                                                         \
    /* P B-frags via in-register half exchange */                             \
    short8 pf[2];                                                             \
    _Pragma("unroll")                                                         \
    for (int ks = 0; ks < 2; ++ks) {                                          \
        unsigned a01 = cvt_pk(p_[8*ks+0], p_[8*ks+1]);                        \
        unsigned a23 = cvt_pk(p_[8*ks+2], p_[8*ks+3]);                        \
        unsigned b01 = cvt_pk(p_[8*ks+4], p_[8*ks+5]);                        \
        unsigned b23 = cvt_pk(p_[8*ks+6], p_[8*ks+7]);                        \
        unsigned ta01 = (unsigned)__shfl_xor((int)a01, 32);                   \
        unsigned ta23 = (unsigned)__shfl_xor((int)a23, 32);                   \
        unsigned tb01 = (unsigned)__shfl_xor((int)b01, 32);                   \
        unsigned tb23 = (unsigned)__shfl_xor((int)b23, 32);                   \
        union { unsigned u[4]; short8 v; } pu;                                \
        pu.u[0] = hi ? tb01 : a01;                                            \
        pu.u[1] = hi ? tb23 : a23;                                            \
        pu.u[2] = hi ? b01 : ta01;                                            \
        pu.u[3] = hi ? b23 : ta23;                                            \
        pf[ks] = pu.v;                                                        \
    }                                                                         \
    /* PV */                                                                  \
    __builtin_amdgcn_s_setprio(1);                                            \
    _Pragma("unroll")                                                         \
    for (int ds = 0; ds < 4; ++ds)                                            \
        _Pragma("unroll")                                                     \
        for (int ks = 0; ks < 2; ++ks)                                        \
            accO[ds] = __builtin_amdgcn_mfma_f32_32x32x16_bf16(               \
                           vfc[ds * 2 + ks], pf[ks], accO[ds], 0, 0, 0);      \
    __builtin_amdgcn_s_setprio(0);                                            \
    if ((TT) == 3) {                                                          \
        asm volatile("s_waitcnt lgkmcnt(0)" ::: "memory");                    \
        __builtin_amdgcn_s_barrier();                                         \
    }                                                                         \
}

    for (int g = 0; g < 8; ++g) {
        STEP_BODY(4 * g + 0, 0, kfA, kfB, mA, mB)
        STEP_BODY(4 * g + 1, 1, kfB, kfA, mB, mA)
        STEP_BODY(4 * g + 2, 2, kfA, kfB, mA, mB)
        STEP_BODY(4 * g + 3, 3, kfB, kfA, mB, mA)
    }
#undef STEP_BODY
#undef LOAD_KF
#undef LOAD_VF
#undef LOAD_MROWS
#undef PACK_MROWS

    // ---- merge partials across wk pairs (loop ended on barrier)
    {
        float* mg = (float*)lds;
        const int slot = (wq * 64 + lane) * 68;
        if (wk == 1) {
            #pragma unroll
            for (int ds = 0; ds < 4; ++ds)
                #pragma unroll
                for (int rr = 0; rr < 4; ++rr) {
                    float4 v;
                    v.x = accO[ds][4*rr+0]; v.y = accO[ds][4*rr+1];
                    v.z = accO[ds][4*rr+2]; v.w = accO[ds][4*rr+3];
                    *(float4*)(mg + slot + ds * 16 + rr * 4) = v;
                }
            mg[slot + 64] = m_run;
            mg[slot + 65] = l_run;
        }
        __syncthreads();
        if (wk == 0) {
            float m1 = mg[slot + 64], l1 = mg[slot + 65];
            float m  = fmaxf(m_run, m1);
            float f0 = ex2(m_run - m), f1 = ex2(m1 - m);
            float l  = l_run * f0 + l1 * f1;
            float inv = (l > 0.f) ? 1.f / l : 0.f;
            float* Ob = O + ((size_t)(b * S_LEN + q0 + wq * 32 + lq)) * DH;
            #pragma unroll
            for (int ds = 0; ds < 4; ++ds)
                #pragma unroll
                for (int rr = 0; rr < 4; ++rr) {
                    float4 part = *(const float4*)(mg + slot + ds * 16 + rr * 4);
                    float4 ov;
                    ov.x = (accO[ds][4*rr+0] * f0 + part.x * f1) * inv;
                    ov.y = (accO[ds][4*rr+1] * f0 + part.y * f1) * inv;
                    ov.z = (accO[ds][4*rr+2] * f0 + part.z * f1) * inv;
                    ov.w = (accO[ds][4*rr+3] * f0 + part.w * f1) * inv;
                    *(float4*)(Ob + ds * 32 + 8 * rr + 4 * hi) = ov;
                }
        }
    }
}

// ============================ fallback (verified round-3 kernel) ============================
#define FB_LDS_BYTES 77824

__global__ __launch_bounds__(256, 2)
void attn_fwd_fb(const float* __restrict__ Q, const float* __restrict__ K,
                 const float* __restrict__ V, const int* __restrict__ M,
                 float* __restrict__ O)
{
    __shared__ __align__(128) char lds[FB_LDS_BYTES];

    const int tid  = threadIdx.x;
    const int lane = tid & 63;
    const int w    = tid >> 6;
    const int c    = lane & 15;
    const int g    = lane >> 4;
    const int qt   = blockIdx.x;
    const int b    = blockIdx.y;
    const int q0   = qt * 64;

    const int rbase = tid >> 5;
    const int c4    = tid & 31;
    const unsigned swk = (unsigned)(c4 * 8) ^ (unsigned)(rbase << 4);
    const int vd    = tid & 127;
    const int vk0   = (tid >> 7) * 32;

    short8 qf[4];
    {
        const float* qrow = Q + ((size_t)(b * S_LEN + q0 + w * 16 + c)) * DH;
        #pragma unroll
        for (int dk = 0; dk < 4; ++dk) {
            const float* p = qrow + dk * 32 + g * 8;
            float4 a  = *(const float4*)(p);
            float4 bb = *(const float4*)(p + 4);
            short8 f;
            f[0] = f2b(a.x * SCALE);  f[1] = f2b(a.y * SCALE);
            f[2] = f2b(a.z * SCALE);  f[3] = f2b(a.w * SCALE);
            f[4] = f2b(bb.x * SCALE); f[5] = f2b(bb.y * SCALE);
            f[6] = f2b(bb.z * SCALE); f[7] = f2b(bb.w * SCALE);
            qf[dk] = f;
        }
    }

    float m_run[4] = {-1e30f, -1e30f, -1e30f, -1e30f};
    float l_run[4] = {0.f, 0.f, 0.f, 0.f};
    floatx4 accO[8];
    #pragma unroll
    for (int i = 0; i < 8; ++i) accO[i] = (floatx4)(0.f);

    const float* Kb = K + (size_t)b * S_LEN * DH;
    const float* Vb = V + (size_t)b * S_LEN * DH;
    const int*   Mb = M + (size_t)b * S_LEN * S_LEN + (size_t)q0 * S_LEN;

    size_t moff[4];
    #pragma unroll
    for (int r = 0; r < 4; ++r)
        moff[r] = (size_t)(w * 16 + 4 * g + r) * S_LEN;

    float4 kreg[8];
    float  vreg[32];
    int    mreg[16];

    #pragma unroll
    for (int i = 0; i < 8; ++i)
        kreg[i] = *(const float4*)(Kb + (size_t)(i * 8 + rbase) * DH + c4 * 4);
    #pragma unroll
    for (int j = 0; j < 32; ++j)
        vreg[j] = Vb[(size_t)(vk0 + j) * DH + vd];
    #pragma unroll
    for (int r = 0; r < 4; ++r)
        #pragma unroll
        for (int n = 0; n < 4; ++n)
            mreg[r * 4 + n] = Mb[moff[r] + n * 16 + c];

    #pragma unroll
    for (int i = 0; i < 8; ++i) {
        float4 kv = kreg[i];
        unsigned long long kp =
              (unsigned long long)f2b(kv.x)
            | ((unsigned long long)f2b(kv.y) << 16)
            | ((unsigned long long)f2b(kv.z) << 32)
            | ((unsigned long long)f2b(kv.w) << 48);
        *(unsigned long long*)(lds + (i * 8 + rbase) * 256 + swk) = kp;
    }
    {
        char* vbase = lds + 32768 + vd * 144 + vk0 * 2;
        #pragma unroll
        for (int i = 0; i < 4; ++i) {
            short8 pk;
            #pragma unroll
            for (int e = 0; e < 8; ++e) pk[e] = f2b(vreg[i * 8 + e]);
            *(short8*)(vbase + i * 16) = pk;
        }
    }
    #pragma unroll
    for (int i = 0; i < 8; ++i)
        kreg[i] = *(const float4*)(Kb + (size_t)(BKV + i * 8 + rbase) * DH + c4 * 4);
    #pragma unroll
    for (int j = 0; j < 32; ++j)
        vreg[j] = Vb[(size_t)(BKV + vk0 + j) * DH + vd];

    __syncthreads();

    char* psw = lds + 69632 + w * 2048;

    for (int step = 0; step < NSTEP; ++step) {
        const int p = step & 1;
        const int kv0 = step * BKV;
        char* KHp = lds + p * 16384;
        char* VTp = lds + 32768 + p * 18432;

        floatx4 accS[4];
        #pragma unroll
        for (int n = 0; n < 4; ++n) accS[n] = (floatx4)(0.f);
        #pragma unroll
        for (int n = 0; n < 4; ++n) {
            const char* krow = KHp + (n * 16 + c) * 256;
            #pragma unroll
            for (int dk = 0; dk < 4; ++dk) {
                unsigned colb = (unsigned)(dk * 64 + g * 16) ^ (unsigned)((c & 7) << 4);
                short8 kf = *(const short8*)(krow + colb);
                accS[n] = __builtin_amdgcn_mfma_f32_16x16x32_bf16(qf[dk], kf, accS[n], 0, 0, 0);
            }
        }

        float pv[4][4];
        float corr[4];
        #pragma unroll
        for (int r = 0; r < 4; ++r) {
            float sv[4];
            #pragma unroll
            for (int n = 0; n < 4; ++n) {
                float s = accS[n][r];
                if (mreg[r * 4 + n]) s = -1e30f;
                sv[n] = s;
            }
            float tm = fmaxf(fmaxf(sv[0], sv[1]), fmaxf(sv[2], sv[3]));
            #pragma unroll
            for (int off = 1; off < 16; off <<= 1)
                tm = fmaxf(tm, __shfl_xor(tm, off, 64));
            float mn = fmaxf(m_run[r], tm);
            corr[r]  = __expf(m_run[r] - mn);
            m_run[r] = mn;
            float ts = 0.f;
            #pragma unroll
            for (int n = 0; n < 4; ++n) { pv[n][r] = __expf(sv[n] - mn); ts += pv[n][r]; }
            #pragma unroll
            for (int off = 1; off < 16; off <<= 1)
                ts += __shfl_xor(ts, off, 64);
            l_run[r] = l_run[r] * corr[r] + ts;
        }
        if (step + 1 < NSTEP) {
            const int kvn = kv0 + BKV;
            #pragma unroll
            for (int r = 0; r < 4; ++r)
                #pragma unroll
                for (int n = 0; n < 4; ++n)
                    mreg[r * 4 + n] = Mb[moff[r] + kvn + n * 16 + c];
        }

        #pragma unroll
        for (int s8 = 0; s8 < 8; ++s8) {
            floatx4 o = accO[s8];
            o[0] *= corr[0]; o[1] *= corr[1]; o[2] *= corr[2]; o[3] *= corr[3];
            accO[s8] = o;
        }

        #pragma unroll
        for (int r = 0; r < 4; ++r) {
            int rl = 4 * g + r;
            #pragma unroll
            for (int n = 0; n < 4; ++n) {
                unsigned colb = (unsigned)((n * 16 + c) * 2) ^ (unsigned)((rl & 7) << 4);
                *(unsigned short*)(psw + rl * 128 + colb) = f2b(pv[n][r]);
            }
        }

        #pragma unroll
        for (int sub = 0; sub < 2; ++sub) {
            unsigned colb = (unsigned)(sub * 64 + g * 16) ^ (unsigned)((c & 7) << 4);
            short8 pf = *(const short8*)(psw + c * 128 + colb);
            #pragma unroll
            for (int s8 = 0; s8 < 8; ++s8) {
                short8 vf = *(const short8*)(VTp + (s8 * 16 + c) * 144 + sub * 64 + g * 16);
                accO[s8] = __builtin_amdgcn_mfma_f32_16x16x32_bf16(pf, vf, accO[s8], 0, 0, 0);
            }
        }

        if (step + 1 < NSTEP) {
            char* KHn = lds + (p ^ 1) * 16384;
            char* VTn = lds + 32768 + (p ^ 1) * 18432;
            #pragma unroll
            for (int i = 0; i < 8; ++i) {
                float4 kv = kreg[i];
                unsigned long long kp =
                      (unsigned long long)f2b(kv.x)
                    | ((unsigned long long)f2b(kv.y) << 16)
                    | ((unsigned long long)f2b(kv.z) << 32)
                    | ((unsigned long long)f2b(kv.w) << 48);
                *(unsigned long long*)(KHn + (i * 8 + rbase) * 256 + swk) = kp;
            }
            char* vbase = VTn + vd * 144 + vk0 * 2;
            #pragma unroll
            for (int i = 0; i < 4; ++i) {
                short8 pk;
                #pragma unroll
                for (int e = 0; e < 8; ++e) pk[e] = f2b(vreg[i * 8 + e]);
                *(short8*)(vbase + i * 16) = pk;
            }
            if (step + 2 < NSTEP) {
                const int kvn2 = kv0 + 2 * BKV;
                #pragma unroll
                for (int i = 0; i < 8; ++i)
                    kreg[i] = *(const float4*)(Kb + (size_t)(kvn2 + i * 8 + rbase) * DH + c4 * 4);
                #pragma unroll
                for (int j = 0; j < 32; ++j)
                    vreg[j] = Vb[(size_t)(kvn2 + vk0 + j) * DH + vd];
            }
        }
        __syncthreads();
    }

    float inv[4];
    #pragma unroll
    for (int r = 0; r < 4; ++r) inv[r] = (l_run[r] > 0.f) ? 1.f / l_run[r] : 0.f;
    float* Ob = O + ((size_t)(b * S_LEN + q0 + w * 16)) * DH;
    #pragma unroll
    for (int s8 = 0; s8 < 8; ++s8) {
        #pragma unroll
        for (int r = 0; r < 4; ++r) {
            Ob[(size_t)(4 * g + r) * DH + s8 * 16 + c] = accO[s8][r] * inv[r];
        }
    }
}

extern "C" void kernel_launch(void* const* d_in, const int* in_sizes, int n_in,
                              void* d_out, int out_size, void* d_ws, size_t ws_size,
                              hipStream_t stream) {
    const float* Q = (const float*)d_in[0];
    const float* K = (const float*)d_in[1];
    const float* V = (const float*)d_in[2];
    const int*   M = (const int*)d_in[3];
    float*       O = (float*)d_out;

    const size_t elems    = (size_t)16 * S_LEN * DH;
    const size_t kv_bytes = elems * sizeof(unsigned short);
    if (ws_size >= 2 * kv_bytes) {
        unsigned short* KFp = (unsigned short*)d_ws;
        unsigned short* VFp = (unsigned short*)d_ws + elems;
        kfrag_make<<<dim3(32, 16), dim3(256), 0, stream>>>(K, KFp);
        vfrag_make<<<dim3(S_LEN / 32, DH / 32, 16), dim3(256), 0, stream>>>(V, VFp);
        attn_fwd<<<dim3(S_LEN / BQ, 16), dim3(256), 0, stream>>>(Q, KFp, VFp, M, O);
    } else {
        attn_fwd_fb<<<dim3(S_LEN / 64, 16), dim3(256), 0, stream>>>(Q, K, V, M, O);
    }
}

// Round 17
// 285.937 us; speedup vs baseline: 1.4057x; 1.4057x over previous
//
#include <hip/hip_runtime.h>
#include <hip/hip_bf16.h>
#include <stdint.h>

typedef __attribute__((ext_vector_type(8)))  short short8;
typedef __attribute__((ext_vector_type(4)))  float floatx4;
typedef __attribute__((ext_vector_type(16))) float floatx16;

#define S_LEN 2048
#define DH    128
#define BQ    64
#define BKV   64
#define NSTEP (S_LEN / BKV)
#define SCALE 0.08838834764831845f                  // 1/sqrt(128)
#define SCALE2 0.12753785429791905f                 // SCALE * log2(e)
#define DTHR 11.541560327111708f                    // 8 * log2(e)

__device__ __forceinline__ float ex2(float x) { return __builtin_amdgcn_exp2f(x); }

__device__ __forceinline__ unsigned short f2b(float f) {
    union { float f; unsigned u; } v; v.f = f;
    unsigned r = v.u + 0x7fffu + ((v.u >> 16) & 1u);
    return (unsigned short)(r >> 16);
}

__device__ __forceinline__ unsigned cvt_pk(float lo, float hi) {
    unsigned r;
    asm("v_cvt_pk_bf16_f32 %0, %1, %2" : "=v"(r) : "v"(lo), "v"(hi));
    return r;
}

// ============================ prepass kernels ============================

// K fragment-major (verified R13-R15): frag F=(wk,dsub,hi,lq) of tile (b,T)
// holds K[b][kv=T*64+wk*32+lq][d=dsub*16+hi*8 .. +8] as 8 bf16.
__global__ __launch_bounds__(256) void kfrag_make(const float* __restrict__ K,
                                                  unsigned short* __restrict__ KF)
{
    const int T = blockIdx.x, b = blockIdx.y;
    const float* Kb = K + ((size_t)b * S_LEN + T * 64) * DH;
    unsigned short* out = KF + ((size_t)(b * 32 + T)) * 1024 * 8;
    #pragma unroll
    for (int i = 0; i < 4; ++i) {
        int F = i * 256 + threadIdx.x;
        int lq = F & 31, h = (F >> 5) & 1, dsub = (F >> 6) & 7, wk = F >> 9;
        const float* src = Kb + (size_t)(wk * 32 + lq) * DH + dsub * 16 + h * 8;
        float4 a = *(const float4*)src, bb = *(const float4*)(src + 4);
        short8 f;
        f[0] = f2b(a.x);  f[1] = f2b(a.y);  f[2] = f2b(a.z);  f[3] = f2b(a.w);
        f[4] = f2b(bb.x); f[5] = f2b(bb.y); f[6] = f2b(bb.z); f[7] = f2b(bb.w);
        *(short8*)(out + (size_t)F * 8) = f;
    }
}

// V fragment-major (verified R13-R15): frag (b,T,ds,wk,ks,hi,lq) holds
// V[b][kv=T*64+wk*32+ks*16+hi*8+e][d=ds*32+lq] transposed.
__global__ __launch_bounds__(256) void vfrag_make(const float* __restrict__ V,
                                                  unsigned short* __restrict__ VF)
{
    __shared__ float t[32][33];
    const int k0 = blockIdx.x * 32, d0 = blockIdx.y * 32, b = blockIdx.z;
    const int tx = threadIdx.x & 31, ty = threadIdx.x >> 5;
    const float* Vb = V + ((size_t)b * S_LEN + k0) * DH + d0;
    #pragma unroll
    for (int i = 0; i < 4; ++i)
        t[ty + 8 * i][tx] = Vb[(size_t)(ty + 8 * i) * DH + tx];
    __syncthreads();
    if (threadIdx.x < 128) {
        const int lq = threadIdx.x & 31;
        const int h  = (threadIdx.x >> 5) & 1;
        const int ks = threadIdx.x >> 6;
        const int T = k0 >> 6, wk = (k0 >> 5) & 1, ds = d0 >> 5;
        short8 f;
        #pragma unroll
        for (int e = 0; e < 8; ++e)
            f[e] = f2b(t[ks * 16 + h * 8 + e][lq]);
        unsigned short* o = VF +
            ((((((size_t)(b * 32 + T) * 4 + ds) * 2 + wk) * 2 + ks) * 2 + h) * 32 + lq) * 8;
        *(short8*)o = f;
    }
}

// ============================ main kernel ============================
// Fragment-major K/V from global (L2), BOTH ping-ponged one step ahead; mask
// ballot-packed in-kernel with 2-step-deep load->pack pipeline (4 rotating
// int4 buffers) into a 4-deep LDS ring; one raw s_barrier per group.
// 32x32 MFMA; waves (wq,wk); in-reg P exchange; per-wave (m,l); end merge.
// LDS: merge 0..34816; packed-mask ring 34816..45056 (4 bufs x 64 rows x 40B)
#define PM_OFF 34816
#define LDS_BYTES 45056

__global__ __launch_bounds__(256, 2)
void attn_fwd(const float* __restrict__ Q, const unsigned short* __restrict__ KF,
              const unsigned short* __restrict__ VF,
              const int* __restrict__ M,
              float* __restrict__ O)
{
    __shared__ __align__(128) char lds[LDS_BYTES];

    const int tid  = threadIdx.x;
    const int lane = tid & 63;
    const int w    = tid >> 6;
    const int wq   = w & 1;
    const int wk   = w >> 1;
    const int lq   = lane & 31;
    const int hi   = lane >> 5;
    const int qt   = blockIdx.x;
    const int b    = blockIdx.y;
    const int q0   = qt * BQ;

    // ---- Q B-fragments (scale*log2e folded)
    short8 qf[8];
    {
        const float* qrow = Q + ((size_t)(b * S_LEN + q0 + wq * 32 + lq)) * DH;
        #pragma unroll
        for (int dsub = 0; dsub < 8; ++dsub) {
            const float* p = qrow + dsub * 16 + hi * 8;
            float4 a  = *(const float4*)(p);
            float4 bb = *(const float4*)(p + 4);
            short8 f;
            f[0] = f2b(a.x * SCALE2);  f[1] = f2b(a.y * SCALE2);
            f[2] = f2b(a.z * SCALE2);  f[3] = f2b(a.w * SCALE2);
            f[4] = f2b(bb.x * SCALE2); f[5] = f2b(bb.y * SCALE2);
            f[6] = f2b(bb.z * SCALE2); f[7] = f2b(bb.w * SCALE2);
            qf[dsub] = f;
        }
    }

    float m_run = -1e30f;
    float l_run = 0.f;
    floatx16 accO[4];
    #pragma unroll
    for (int i = 0; i < 4; ++i) accO[i] = (floatx16)(0.f);

    const unsigned short* KFl = KF + (((size_t)(b * 32) * 2 + wk) * 512
                                      + (size_t)hi * 32 + lq) * 8;
    const unsigned short* VFl = VF + ((((size_t)(b * 32) * 4 * 2 + wk) * 2) * 2 * 32
                                      + (size_t)hi * 32 + lq) * 8;

    const int* Mq = M + (size_t)b * S_LEN * S_LEN + (size_t)q0 * S_LEN;

    int4 m0[4], m1[4], m2[4], m3[4];
    short8 kfA[8], kfB[8], vfA[8], vfB[8];
    unsigned long long mgc[4];

#define LOAD_KF(DST, T) {                                                     \
    const unsigned short* kp_ = KFl + (size_t)(T) * (2 * 512 * 8);            \
    _Pragma("unroll")                                                         \
    for (int dsub = 0; dsub < 8; ++dsub)                                      \
        DST[dsub] = *(const short8*)(kp_ + dsub * 512);                       \
}

#define LOAD_VF(DST, T) {                                                     \
    _Pragma("unroll")                                                         \
    for (int ds = 0; ds < 4; ++ds)                                            \
        _Pragma("unroll")                                                     \
        for (int ks = 0; ks < 2; ++ks)                                        \
            DST[ds * 2 + ks] = *(const short8*)(VFl                           \
                + ((size_t)(T) * 16 + ds * 4 + ks) * (2 * 32 * 8));           \
}

#define LOAD_MROWS(DST, G, SB) {                                              \
    _Pragma("unroll")                                                         \
    for (int rr = 0; rr < 4; ++rr)                                            \
        DST[rr] = *(const int4*)(Mq + (size_t)(w * 16 + (SB) * 4 + rr) * S_LEN \
                                 + (G) * 256 + 4 * lane);                     \
}
#define PACK_MROWS(SRC, PBUF, SB) {                                           \
    char* pms_ = lds + PM_OFF + (PBUF) * 2560;                                \
    _Pragma("unroll")                                                         \
    for (int rr = 0; rr < 4; ++rr) {                                          \
        int4 mm = SRC[rr];                                                    \
        unsigned long long b0 = __ballot(mm.x != 0);                          \
        unsigned long long b1 = __ballot(mm.y != 0);                          \
        unsigned long long b2 = __ballot(mm.z != 0);                          \
        unsigned long long b3 = __ballot(mm.w != 0);                          \
        if (lane == 0) {                                                      \
            char* rp_ = pms_ + (w * 16 + (SB) * 4 + rr) * 40;                 \
            *(unsigned long long*)(rp_ +  0) = b0;                            \
            *(unsigned long long*)(rp_ +  8) = b1;                            \
            *(unsigned long long*)(rp_ + 16) = b2;                            \
            *(unsigned long long*)(rp_ + 24) = b3;                            \
        }                                                                     \
    }                                                                         \
}

    // ---- prologue: pack groups 0 and 1 directly; K(0)/V(0) into A buffers
    LOAD_KF(kfA, 0);
    LOAD_VF(vfA, 0);
    #pragma unroll
    for (int gg = 0; gg < 2; ++gg)
        #pragma unroll
        for (int sb = 0; sb < 4; ++sb) {
            int4 t_[4];
            LOAD_MROWS(t_, gg, sb)
            PACK_MROWS(t_, gg, sb)
        }
    __syncthreads();

// step T: consume KFC/VFC (loaded at T-1); load KFN/VFN for T+1;
// load MLD (mask rows for group (T>>2)+2, sub T&3); pack MPK (loaded at T-2).
#define STEP_BODY(T, TT, KFC, KFN, VFC, VFN, MLD, MPK) {                      \
    if ((T) + 1 < NSTEP) LOAD_KF(KFN, (T) + 1);                               \
    if ((T) + 1 < NSTEP) LOAD_VF(VFN, (T) + 1);                               \
    if ((T) < 24) LOAD_MROWS(MLD, ((T) >> 2) + 2, TT)                         \
    if ((T) >= 2 && (T) <= 25) {                                              \
        PACK_MROWS(MPK, (((((T) - 2) >> 2) + 2) & 3), (((T) - 2) & 3))        \
    }                                                                         \
    if ((TT) == 0) {                                                          \
        const char* pmb_ = lds + PM_OFF + (((T) >> 2) & 3) * 2560             \
                           + (wq * 32 + lq) * 40;                             \
        mgc[0] = *(const unsigned long long*)(pmb_ + 0);                      \
        mgc[1] = *(const unsigned long long*)(pmb_ + 8);                      \
        mgc[2] = *(const unsigned long long*)(pmb_ + 16);                     \
        mgc[3] = *(const unsigned long long*)(pmb_ + 24);                     \
    }                                                                         \
    /* QK^T from KFC (loaded one full step ago) */                            \
    floatx16 accS = (floatx16)(0.f);                                          \
    __builtin_amdgcn_s_setprio(1);                                            \
    _Pragma("unroll")                                                         \
    for (int dsub = 0; dsub < 8; ++dsub)                                      \
        accS = __builtin_amdgcn_mfma_f32_32x32x16_bf16(                       \
                   KFC[dsub], qf[dsub], accS, 0, 0, 0);                       \
    __builtin_amdgcn_s_setprio(0);                                            \
    const int base_ = (TT) * 16 + wk * 8 + hi;                                \
    unsigned mb0 = (unsigned)(mgc[0] >> base_);                               \
    unsigned mb1 = (unsigned)(mgc[1] >> base_);                               \
    unsigned mb2 = (unsigned)(mgc[2] >> base_);                               \
    unsigned mb3 = (unsigned)(mgc[3] >> base_);                               \
    float p_[16];                                                             \
    _Pragma("unroll")                                                         \
    for (int j = 0; j < 4; ++j) {                                             \
        p_[4*j+0] = ((mb0 >> (2*j)) & 1u) ? -1e30f : accS[4*j+0];             \
        p_[4*j+1] = ((mb1 >> (2*j)) & 1u) ? -1e30f : accS[4*j+1];             \
        p_[4*j+2] = ((mb2 >> (2*j)) & 1u) ? -1e30f : accS[4*j+2];             \
        p_[4*j+3] = ((mb3 >> (2*j)) & 1u) ? -1e30f : accS[4*j+3];             \
    }                                                                         \
    float mx = p_[0];                                                         \
    _Pragma("unroll")                                                         \
    for (int r = 1; r < 16; ++r) mx = fmaxf(mx, p_[r]);                       \
    mx = fmaxf(mx, __shfl_xor(mx, 32));                                       \
    int need = __any(mx - m_run > DTHR);                                      \
    float corr = 1.0f;                                                        \
    if (need) {                                                               \
        float mn = fmaxf(m_run, mx);                                          \
        corr = ex2(m_run - mn);                                               \
        m_run = mn;                                                           \
    }                                                                         \
    float ts = 0.f;                                                           \
    _Pragma("unroll")                                                         \
    for (int r = 0; r < 16; ++r) { p_[r] = ex2(p_[r] - m_run); ts += p_[r]; } \
    ts += __shfl_xor(ts, 32);                                                 \
    if (need) {                                                               \
        l_run = l_run * corr + ts;                                            \
        _Pragma("unroll")                                                     \
        for (int ds = 0; ds < 4; ++ds) {                                      \
            floatx16 o = accO[ds];                                            \
            _Pragma("unroll")                                                 \
            for (int r = 0; r < 16; ++r) o[r] *= corr;                        \
            accO[ds] = o;                                                     \
        }                                                                     \
    } else {                                                                  \
        l_run += ts;                                                          \
    }                                                                         \
    /* P B-frags via in-register half exchange */                             \
    short8 pf[2];                                                             \
    _Pragma("unroll")                                                         \
    for (int ks = 0; ks < 2; ++ks) {                                          \
        unsigned a01 = cvt_pk(p_[8*ks+0], p_[8*ks+1]);                        \
        unsigned a23 = cvt_pk(p_[8*ks+2], p_[8*ks+3]);                        \
        unsigned b01 = cvt_pk(p_[8*ks+4], p_[8*ks+5]);                        \
        unsigned b23 = cvt_pk(p_[8*ks+6], p_[8*ks+7]);                        \
        unsigned ta01 = (unsigned)__shfl_xor((int)a01, 32);                   \
        unsigned ta23 = (unsigned)__shfl_xor((int)a23, 32);                   \
        unsigned tb01 = (unsigned)__shfl_xor((int)b01, 32);                   \
        unsigned tb23 = (unsigned)__shfl_xor((int)b23, 32);                   \
        union { unsigned u[4]; short8 v; } pu;                                \
        pu.u[0] = hi ? tb01 : a01;                                            \
        pu.u[1] = hi ? tb23 : a23;                                            \
        pu.u[2] = hi ? b01 : ta01;                                            \
        pu.u[3] = hi ? b23 : ta23;                                            \
        pf[ks] = pu.v;                                                        \
    }                                                                         \
    /* PV from VFC (loaded one full step ago) */                              \
    __builtin_amdgcn_s_setprio(1);                                            \
    _Pragma("unroll")                                                         \
    for (int ds = 0; ds < 4; ++ds)                                            \
        _Pragma("unroll")                                                     \
        for (int ks = 0; ks < 2; ++ks)                                        \
            accO[ds] = __builtin_amdgcn_mfma_f32_32x32x16_bf16(               \
                           VFC[ds * 2 + ks], pf[ks], accO[ds], 0, 0, 0);      \
    __builtin_amdgcn_s_setprio(0);                                            \
    if ((TT) == 3) {                                                          \
        asm volatile("s_waitcnt lgkmcnt(0)" ::: "memory");                    \
        __builtin_amdgcn_s_barrier();                                         \
    }                                                                         \
}

    for (int g = 0; g < 8; ++g) {
        STEP_BODY(4 * g + 0, 0, kfA, kfB, vfA, vfB, m0, m2)
        STEP_BODY(4 * g + 1, 1, kfB, kfA, vfB, vfA, m1, m3)
        STEP_BODY(4 * g + 2, 2, kfA, kfB, vfA, vfB, m2, m0)
        STEP_BODY(4 * g + 3, 3, kfB, kfA, vfB, vfA, m3, m1)
    }
#undef STEP_BODY
#undef LOAD_KF
#undef LOAD_VF
#undef LOAD_MROWS
#undef PACK_MROWS

    // ---- merge partials across wk pairs (loop ended on barrier)
    {
        float* mg = (float*)lds;
        const int slot = (wq * 64 + lane) * 68;
        if (wk == 1) {
            #pragma unroll
            for (int ds = 0; ds < 4; ++ds)
                #pragma unroll
                for (int rr = 0; rr < 4; ++rr) {
                    float4 v;
                    v.x = accO[ds][4*rr+0]; v.y = accO[ds][4*rr+1];
                    v.z = accO[ds][4*rr+2]; v.w = accO[ds][4*rr+3];
                    *(float4*)(mg + slot + ds * 16 + rr * 4) = v;
                }
            mg[slot + 64] = m_run;
            mg[slot + 65] = l_run;
        }
        __syncthreads();
        if (wk == 0) {
            float m1v = mg[slot + 64], l1 = mg[slot + 65];
            float m  = fmaxf(m_run, m1v);
            float f0 = ex2(m_run - m), f1 = ex2(m1v - m);
            float l  = l_run * f0 + l1 * f1;
            float inv = (l > 0.f) ? 1.f / l : 0.f;
            float* Ob = O + ((size_t)(b * S_LEN + q0 + wq * 32 + lq)) * DH;
            #pragma unroll
            for (int ds = 0; ds < 4; ++ds)
                #pragma unroll
                for (int rr = 0; rr < 4; ++rr) {
                    float4 part = *(const float4*)(mg + slot + ds * 16 + rr * 4);
                    float4 ov;
                    ov.x = (accO[ds][4*rr+0] * f0 + part.x * f1) * inv;
                    ov.y = (accO[ds][4*rr+1] * f0 + part.y * f1) * inv;
                    ov.z = (accO[ds][4*rr+2] * f0 + part.z * f1) * inv;
                    ov.w = (accO[ds][4*rr+3] * f0 + part.w * f1) * inv;
                    *(float4*)(Ob + ds * 32 + 8 * rr + 4 * hi) = ov;
                }
        }
    }
}

// ============================ fallback (verified round-3 kernel) ============================
#define FB_LDS_BYTES 77824

__global__ __launch_bounds__(256, 2)
void attn_fwd_fb(const float* __restrict__ Q, const float* __restrict__ K,
                 const float* __restrict__ V, const int* __restrict__ M,
                 float* __restrict__ O)
{
    __shared__ __align__(128) char lds[FB_LDS_BYTES];

    const int tid  = threadIdx.x;
    const int lane = tid & 63;
    const int w    = tid >> 6;
    const int c    = lane & 15;
    const int g    = lane >> 4;
    const int qt   = blockIdx.x;
    const int b    = blockIdx.y;
    const int q0   = qt * 64;

    const int rbase = tid >> 5;
    const int c4    = tid & 31;
    const unsigned swk = (unsigned)(c4 * 8) ^ (unsigned)(rbase << 4);
    const int vd    = tid & 127;
    const int vk0   = (tid >> 7) * 32;

    short8 qf[4];
    {
        const float* qrow = Q + ((size_t)(b * S_LEN + q0 + w * 16 + c)) * DH;
        #pragma unroll
        for (int dk = 0; dk < 4; ++dk) {
            const float* p = qrow + dk * 32 + g * 8;
            float4 a  = *(const float4*)(p);
            float4 bb = *(const float4*)(p + 4);
            short8 f;
            f[0] = f2b(a.x * SCALE);  f[1] = f2b(a.y * SCALE);
            f[2] = f2b(a.z * SCALE);  f[3] = f2b(a.w * SCALE);
            f[4] = f2b(bb.x * SCALE); f[5] = f2b(bb.y * SCALE);
            f[6] = f2b(bb.z * SCALE); f[7] = f2b(bb.w * SCALE);
            qf[dk] = f;
        }
    }

    float m_run[4] = {-1e30f, -1e30f, -1e30f, -1e30f};
    float l_run[4] = {0.f, 0.f, 0.f, 0.f};
    floatx4 accO[8];
    #pragma unroll
    for (int i = 0; i < 8; ++i) accO[i] = (floatx4)(0.f);

    const float* Kb = K + (size_t)b * S_LEN * DH;
    const float* Vb = V + (size_t)b * S_LEN * DH;
    const int*   Mb = M + (size_t)b * S_LEN * S_LEN + (size_t)q0 * S_LEN;

    size_t moff[4];
    #pragma unroll
    for (int r = 0; r < 4; ++r)
        moff[r] = (size_t)(w * 16 + 4 * g + r) * S_LEN;

    float4 kreg[8];
    float  vreg[32];
    int    mreg[16];

    #pragma unroll
    for (int i = 0; i < 8; ++i)
        kreg[i] = *(const float4*)(Kb + (size_t)(i * 8 + rbase) * DH + c4 * 4);
    #pragma unroll
    for (int j = 0; j < 32; ++j)
        vreg[j] = Vb[(size_t)(vk0 + j) * DH + vd];
    #pragma unroll
    for (int r = 0; r < 4; ++r)
        #pragma unroll
        for (int n = 0; n < 4; ++n)
            mreg[r * 4 + n] = Mb[moff[r] + n * 16 + c];

    #pragma unroll
    for (int i = 0; i < 8; ++i) {
        float4 kv = kreg[i];
        unsigned long long kp =
              (unsigned long long)f2b(kv.x)
            | ((unsigned long long)f2b(kv.y) << 16)
            | ((unsigned long long)f2b(kv.z) << 32)
            | ((unsigned long long)f2b(kv.w) << 48);
        *(unsigned long long*)(lds + (i * 8 + rbase) * 256 + swk) = kp;
    }
    {
        char* vbase = lds + 32768 + vd * 144 + vk0 * 2;
        #pragma unroll
        for (int i = 0; i < 4; ++i) {
            short8 pk;
            #pragma unroll
            for (int e = 0; e < 8; ++e) pk[e] = f2b(vreg[i * 8 + e]);
            *(short8*)(vbase + i * 16) = pk;
        }
    }
    #pragma unroll
    for (int i = 0; i < 8; ++i)
        kreg[i] = *(const float4*)(Kb + (size_t)(BKV + i * 8 + rbase) * DH + c4 * 4);
    #pragma unroll
    for (int j = 0; j < 32; ++j)
        vreg[j] = Vb[(size_t)(BKV + vk0 + j) * DH + vd];

    __syncthreads();

    char* psw = lds + 69632 + w * 2048;

    for (int step = 0; step < NSTEP; ++step) {
        const int p = step & 1;
        const int kv0 = step * BKV;
        char* KHp = lds + p * 16384;
        char* VTp = lds + 32768 + p * 18432;

        floatx4 accS[4];
        #pragma unroll
        for (int n = 0; n < 4; ++n) accS[n] = (floatx4)(0.f);
        #pragma unroll
        for (int n = 0; n < 4; ++n) {
            const char* krow = KHp + (n * 16 + c) * 256;
            #pragma unroll
            for (int dk = 0; dk < 4; ++dk) {
                unsigned colb = (unsigned)(dk * 64 + g * 16) ^ (unsigned)((c & 7) << 4);
                short8 kf = *(const short8*)(krow + colb);
                accS[n] = __builtin_amdgcn_mfma_f32_16x16x32_bf16(qf[dk], kf, accS[n], 0, 0, 0);
            }
        }

        float pv[4][4];
        float corr[4];
        #pragma unroll
        for (int r = 0; r < 4; ++r) {
            float sv[4];
            #pragma unroll
            for (int n = 0; n < 4; ++n) {
                float s = accS[n][r];
                if (mreg[r * 4 + n]) s = -1e30f;
                sv[n] = s;
            }
            float tm = fmaxf(fmaxf(sv[0], sv[1]), fmaxf(sv[2], sv[3]));
            #pragma unroll
            for (int off = 1; off < 16; off <<= 1)
                tm = fmaxf(tm, __shfl_xor(tm, off, 64));
            float mn = fmaxf(m_run[r], tm);
            corr[r]  = __expf(m_run[r] - mn);
            m_run[r] = mn;
            float ts = 0.f;
            #pragma unroll
            for (int n = 0; n < 4; ++n) { pv[n][r] = __expf(sv[n] - mn); ts += pv[n][r]; }
            #pragma unroll
            for (int off = 1; off < 16; off <<= 1)
                ts += __shfl_xor(ts, off, 64);
            l_run[r] = l_run[r] * corr[r] + ts;
        }
        if (step + 1 < NSTEP) {
            const int kvn = kv0 + BKV;
            #pragma unroll
            for (int r = 0; r < 4; ++r)
                #pragma unroll
                for (int n = 0; n < 4; ++n)
                    mreg[r * 4 + n] = Mb[moff[r] + kvn + n * 16 + c];
        }

        #pragma unroll
        for (int s8 = 0; s8 < 8; ++s8) {
            floatx4 o = accO[s8];
            o[0] *= corr[0]; o[1] *= corr[1]; o[2] *= corr[2]; o[3] *= corr[3];
            accO[s8] = o;
        }

        #pragma unroll
        for (int r = 0; r < 4; ++r) {
            int rl = 4 * g + r;
            #pragma unroll
            for (int n = 0; n < 4; ++n) {
                unsigned colb = (unsigned)((n * 16 + c) * 2) ^ (unsigned)((rl & 7) << 4);
                *(unsigned short*)(psw + rl * 128 + colb) = f2b(pv[n][r]);
            }
        }

        #pragma unroll
        for (int sub = 0; sub < 2; ++sub) {
            unsigned colb = (unsigned)(sub * 64 + g * 16) ^ (unsigned)((c & 7) << 4);
            short8 pf = *(const short8*)(psw + c * 128 + colb);
            #pragma unroll
            for (int s8 = 0; s8 < 8; ++s8) {
                short8 vf = *(const short8*)(VTp + (s8 * 16 + c) * 144 + sub * 64 + g * 16);
                accO[s8] = __builtin_amdgcn_mfma_f32_16x16x32_bf16(pf, vf, accO[s8], 0, 0, 0);
            }
        }

        if (step + 1 < NSTEP) {
            char* KHn = lds + (p ^ 1) * 16384;
            char* VTn = lds + 32768 + (p ^ 1) * 18432;
            #pragma unroll
            for (int i = 0; i < 8; ++i) {
                float4 kv = kreg[i];
                unsigned long long kp =
                      (unsigned long long)f2b(kv.x)
                    | ((unsigned long long)f2b(kv.y) << 16)
                    | ((unsigned long long)f2b(kv.z) << 32)
                    | ((unsigned long long)f2b(kv.w) << 48);
                *(unsigned long long*)(KHn + (i * 8 + rbase) * 256 + swk) = kp;
            }
            char* vbase = VTn + vd * 144 + vk0 * 2;
            #pragma unroll
            for (int i = 0; i < 4; ++i) {
                short8 pk;
                #pragma unroll
                for (int e = 0; e < 8; ++e) pk[e] = f2b(vreg[i * 8 + e]);
                *(short8*)(vbase + i * 16) = pk;
            }
            if (step + 2 < NSTEP) {
                const int kvn2 = kv0 + 2 * BKV;
                #pragma unroll
                for (int i = 0; i < 8; ++i)
                    kreg[i] = *(const float4*)(Kb + (size_t)(kvn2 + i * 8 + rbase) * DH + c4 * 4);
                #pragma unroll
                for (int j = 0; j < 32; ++j)
                    vreg[j] = Vb[(size_t)(kvn2 + vk0 + j) * DH + vd];
            }
        }
        __syncthreads();
    }

    float inv[4];
    #pragma unroll
    for (int r = 0; r < 4; ++r) inv[r] = (l_run[r] > 0.f) ? 1.f / l_run[r] : 0.f;
    float* Ob = O + ((size_t)(b * S_LEN + q0 + w * 16)) * DH;
    #pragma unroll
    for (int s8 = 0; s8 < 8; ++s8) {
        #pragma unroll
        for (int r = 0; r < 4; ++r) {
            Ob[(size_t)(4 * g + r) * DH + s8 * 16 + c] = accO[s8][r] * inv[r];
        }
    }
}

extern "C" void kernel_launch(void* const* d_in, const int* in_sizes, int n_in,
                              void* d_out, int out_size, void* d_ws, size_t ws_size,
                              hipStream_t stream) {
    const float* Q = (const float*)d_in[0];
    const float* K = (const float*)d_in[1];
    const float* V = (const float*)d_in[2];
    const int*   M = (const int*)d_in[3];
    float*       O = (float*)d_out;

    const size_t elems    = (size_t)16 * S_LEN * DH;
    const size_t kv_bytes = elems * sizeof(unsigned short);
    if (ws_size >= 2 * kv_bytes) {
        unsigned short* KFp = (unsigned short*)d_ws;
        unsigned short* VFp = (unsigned short*)d_ws + elems;
        kfrag_make<<<dim3(32, 16), dim3(256), 0, stream>>>(K, KFp);
        vfrag_make<<<dim3(S_LEN / 32, DH / 32, 16), dim3(256), 0, stream>>>(V, VFp);
        attn_fwd<<<dim3(S_LEN / BQ, 16), dim3(256), 0, stream>>>(Q, KFp, VFp, M, O);
    } else {
        attn_fwd_fb<<<dim3(S_LEN / 64, 16), dim3(256), 0, stream>>>(Q, K, V, M, O);
    }
}

// Round 18
// 170.652 us; speedup vs baseline: 2.3554x; 1.6756x over previous
//
#include <hip/hip_runtime.h>
#include <hip/hip_bf16.h>
#include <stdint.h>

typedef __attribute__((ext_vector_type(8)))  short short8;
typedef __attribute__((ext_vector_type(4)))  float floatx4;
typedef __attribute__((ext_vector_type(16))) float floatx16;

#define S_LEN 2048
#define DH    128
#define BQ    64
#define BKV   64
#define NSTEP (S_LEN / BKV)
#define SCALE 0.08838834764831845f                  // 1/sqrt(128)
#define SCALE2 0.12753785429791905f                 // SCALE * log2(e)
#define DTHR 11.541560327111708f                    // 8 * log2(e)

__device__ __forceinline__ float ex2(float x) { return __builtin_amdgcn_exp2f(x); }

__device__ __forceinline__ unsigned short f2b(float f) {
    union { float f; unsigned u; } v; v.f = f;
    unsigned r = v.u + 0x7fffu + ((v.u >> 16) & 1u);
    return (unsigned short)(r >> 16);
}

__device__ __forceinline__ unsigned cvt_pk(float lo, float hi) {
    unsigned r;
    asm("v_cvt_pk_bf16_f32 %0, %1, %2" : "=v"(r) : "v"(lo), "v"(hi));
    return r;
}

// ============================ prepass kernels ============================

__global__ __launch_bounds__(256) void kfrag_make(const float* __restrict__ K,
                                                  unsigned short* __restrict__ KF)
{
    const int T = blockIdx.x, b = blockIdx.y;
    const float* Kb = K + ((size_t)b * S_LEN + T * 64) * DH;
    unsigned short* out = KF + ((size_t)(b * 32 + T)) * 1024 * 8;
    #pragma unroll
    for (int i = 0; i < 4; ++i) {
        int F = i * 256 + threadIdx.x;
        int lq = F & 31, h = (F >> 5) & 1, dsub = (F >> 6) & 7, wk = F >> 9;
        const float* src = Kb + (size_t)(wk * 32 + lq) * DH + dsub * 16 + h * 8;
        float4 a = *(const float4*)src, bb = *(const float4*)(src + 4);
        short8 f;
        f[0] = f2b(a.x);  f[1] = f2b(a.y);  f[2] = f2b(a.z);  f[3] = f2b(a.w);
        f[4] = f2b(bb.x); f[5] = f2b(bb.y); f[6] = f2b(bb.z); f[7] = f2b(bb.w);
        *(short8*)(out + (size_t)F * 8) = f;
    }
}

__global__ __launch_bounds__(256) void vfrag_make(const float* __restrict__ V,
                                                  unsigned short* __restrict__ VF)
{
    __shared__ float t[32][33];
    const int k0 = blockIdx.x * 32, d0 = blockIdx.y * 32, b = blockIdx.z;
    const int tx = threadIdx.x & 31, ty = threadIdx.x >> 5;
    const float* Vb = V + ((size_t)b * S_LEN + k0) * DH + d0;
    #pragma unroll
    for (int i = 0; i < 4; ++i)
        t[ty + 8 * i][tx] = Vb[(size_t)(ty + 8 * i) * DH + tx];
    __syncthreads();
    if (threadIdx.x < 128) {
        const int lq = threadIdx.x & 31;
        const int h  = (threadIdx.x >> 5) & 1;
        const int ks = threadIdx.x >> 6;
        const int T = k0 >> 6, wk = (k0 >> 5) & 1, ds = d0 >> 5;
        short8 f;
        #pragma unroll
        for (int e = 0; e < 8; ++e)
            f[e] = f2b(t[ks * 16 + h * 8 + e][lq]);
        unsigned short* o = VF +
            ((((((size_t)(b * 32 + T) * 4 + ds) * 2 + wk) * 2 + ks) * 2 + h) * 32 + lq) * 8;
        *(short8*)o = f;
    }
}

// ============================ split attention kernel ============================
// EXACT inner loop of the 113.5us kernel, kv-split over blockIdx.z (16 steps
// each), writing unnormalized partials + (m,l). Mask ring overlaid on merge
// scratch (ring dead before epilogue) -> LDS 34816 -> up to 4 blocks/CU.
#define SP_LDS 34816

__global__ __launch_bounds__(256)
void attn_split(const float* __restrict__ Q, const unsigned short* __restrict__ KF,
                const unsigned short* __restrict__ VF,
                const int* __restrict__ M,
                float* __restrict__ OP, float* __restrict__ ML)
{
    __shared__ __align__(128) char lds[SP_LDS];

    const int tid  = threadIdx.x;
    const int lane = tid & 63;
    const int w    = tid >> 6;
    const int wq   = w & 1;
    const int wk   = w >> 1;
    const int lq   = lane & 31;
    const int hi   = lane >> 5;
    const int qt   = blockIdx.x;
    const int b    = blockIdx.y;
    const int zh   = blockIdx.z;           // kv half: steps zh*16 .. zh*16+15
    const int q0   = qt * BQ;

    short8 qf[8];
    {
        const float* qrow = Q + ((size_t)(b * S_LEN + q0 + wq * 32 + lq)) * DH;
        #pragma unroll
        for (int dsub = 0; dsub < 8; ++dsub) {
            const float* p = qrow + dsub * 16 + hi * 8;
            float4 a  = *(const float4*)(p);
            float4 bb = *(const float4*)(p + 4);
            short8 f;
            f[0] = f2b(a.x * SCALE2);  f[1] = f2b(a.y * SCALE2);
            f[2] = f2b(a.z * SCALE2);  f[3] = f2b(a.w * SCALE2);
            f[4] = f2b(bb.x * SCALE2); f[5] = f2b(bb.y * SCALE2);
            f[6] = f2b(bb.z * SCALE2); f[7] = f2b(bb.w * SCALE2);
            qf[dsub] = f;
        }
    }

    float m_run = -1e30f;
    float l_run = 0.f;
    floatx16 accO[4];
    #pragma unroll
    for (int i = 0; i < 4; ++i) accO[i] = (floatx16)(0.f);

    const unsigned short* KFl = KF + (((size_t)(b * 32) * 2 + wk) * 512
                                      + (size_t)hi * 32 + lq) * 8;
    const unsigned short* VFl = VF + ((((size_t)(b * 32) * 4 * 2 + wk) * 2) * 2 * 32
                                      + (size_t)hi * 32 + lq) * 8;

    const int* Mq = M + (size_t)b * S_LEN * S_LEN + (size_t)q0 * S_LEN;

    int4 mA[4], mB[4];
    short8 kfc[8], vfc[8];
    unsigned long long mgc[4];

#define LOAD_KF(T) {                                                          \
    const unsigned short* kp_ = KFl + (size_t)(T) * (2 * 512 * 8);            \
    _Pragma("unroll")                                                         \
    for (int dsub = 0; dsub < 8; ++dsub)                                      \
        kfc[dsub] = *(const short8*)(kp_ + dsub * 512);                       \
}
#define LOAD_VF(T) {                                                          \
    _Pragma("unroll")                                                         \
    for (int ds = 0; ds < 4; ++ds)                                            \
        _Pragma("unroll")                                                     \
        for (int ks = 0; ks < 2; ++ks)                                        \
            vfc[ds * 2 + ks] = *(const short8*)(VFl                           \
                + ((size_t)(T) * 16 + ds * 4 + ks) * (2 * 32 * 8));           \
}
#define LOAD_MROWS(DST, G, SB) {                                              \
    _Pragma("unroll")                                                         \
    for (int rr = 0; rr < 4; ++rr)                                            \
        DST[rr] = *(const int4*)(Mq + (size_t)(w * 16 + (SB) * 4 + rr) * S_LEN \
                                 + (size_t)(G) * 256 + 4 * lane);             \
}
#define PACK_MROWS(SRC, PBUF, SB) {                                           \
    char* pms_ = lds + (PBUF) * 2560;                                         \
    _Pragma("unroll")                                                         \
    for (int rr = 0; rr < 4; ++rr) {                                          \
        int4 mm = SRC[rr];                                                    \
        unsigned long long b0 = __ballot(mm.x != 0);                          \
        unsigned long long b1 = __ballot(mm.y != 0);                          \
        unsigned long long b2 = __ballot(mm.z != 0);                          \
        unsigned long long b3 = __ballot(mm.w != 0);                          \
        if (lane == 0) {                                                      \
            char* rp_ = pms_ + (w * 16 + (SB) * 4 + rr) * 40;                 \
            *(unsigned long long*)(rp_ +  0) = b0;                            \
            *(unsigned long long*)(rp_ +  8) = b1;                            \
            *(unsigned long long*)(rp_ + 16) = b2;                            \
            *(unsigned long long*)(rp_ + 24) = b3;                            \
        }                                                                     \
    }                                                                         \
}

    // ---- prologue: pack local groups 0,1 (global zh*4 +0,+1) into slots 0,1
    #pragma unroll
    for (int gg = 0; gg < 2; ++gg)
        #pragma unroll
        for (int sb = 0; sb < 4; ++sb) {
            int4 t_[4];
            LOAD_MROWS(t_, zh * 4 + gg, sb)
            PACK_MROWS(t_, gg, sb)
        }
    __syncthreads();

#define STEP_BODY(K, MCUR, MOLD) {                                            \
    const int lt = 4 * g + (K);                                               \
    const int T  = zh * 16 + lt;                                              \
    LOAD_KF(T);                                                               \
    LOAD_VF(T);                                                               \
    if (lt < 8) LOAD_MROWS(MCUR, zh * 4 + g + 2, K)                           \
    if (lt >= 1 && lt <= 8) {                                                 \
        PACK_MROWS(MOLD, ((((lt - 1) >> 2) + 2) & 3), ((lt - 1) & 3))         \
    }                                                                         \
    if ((K) == 0) {                                                           \
        const char* pmb_ = lds + (g & 3) * 2560 + (wq * 32 + lq) * 40;        \
        mgc[0] = *(const unsigned long long*)(pmb_ + 0);                      \
        mgc[1] = *(const unsigned long long*)(pmb_ + 8);                      \
        mgc[2] = *(const unsigned long long*)(pmb_ + 16);                     \
        mgc[3] = *(const unsigned long long*)(pmb_ + 24);                     \
    }                                                                         \
    floatx16 accS = (floatx16)(0.f);                                          \
    __builtin_amdgcn_s_setprio(1);                                            \
    _Pragma("unroll")                                                         \
    for (int dsub = 0; dsub < 8; ++dsub)                                      \
        accS = __builtin_amdgcn_mfma_f32_32x32x16_bf16(                       \
                   kfc[dsub], qf[dsub], accS, 0, 0, 0);                       \
    __builtin_amdgcn_s_setprio(0);                                            \
    const int base_ = (K) * 16 + wk * 8 + hi;                                 \
    unsigned mb0 = (unsigned)(mgc[0] >> base_);                               \
    unsigned mb1 = (unsigned)(mgc[1] >> base_);                               \
    unsigned mb2 = (unsigned)(mgc[2] >> base_);                               \
    unsigned mb3 = (unsigned)(mgc[3] >> base_);                               \
    float p_[16];                                                             \
    _Pragma("unroll")                                                         \
    for (int j = 0; j < 4; ++j) {                                             \
        p_[4*j+0] = ((mb0 >> (2*j)) & 1u) ? -1e30f : accS[4*j+0];             \
        p_[4*j+1] = ((mb1 >> (2*j)) & 1u) ? -1e30f : accS[4*j+1];             \
        p_[4*j+2] = ((mb2 >> (2*j)) & 1u) ? -1e30f : accS[4*j+2];             \
        p_[4*j+3] = ((mb3 >> (2*j)) & 1u) ? -1e30f : accS[4*j+3];             \
    }                                                                         \
    float mx = p_[0];                                                         \
    _Pragma("unroll")                                                         \
    for (int r = 1; r < 16; ++r) mx = fmaxf(mx, p_[r]);                       \
    mx = fmaxf(mx, __shfl_xor(mx, 32));                                       \
    int need = __any(mx - m_run > DTHR);                                      \
    float corr = 1.0f;                                                        \
    if (need) {                                                               \
        float mn = fmaxf(m_run, mx);                                          \
        corr = ex2(m_run - mn);                                               \
        m_run = mn;                                                           \
    }                                                                         \
    float ts = 0.f;                                                           \
    _Pragma("unroll")                                                         \
    for (int r = 0; r < 16; ++r) { p_[r] = ex2(p_[r] - m_run); ts += p_[r]; } \
    ts += __shfl_xor(ts, 32);                                                 \
    if (need) {                                                               \
        l_run = l_run * corr + ts;                                            \
        _Pragma("unroll")                                                     \
        for (int ds = 0; ds < 4; ++ds) {                                      \
            floatx16 o = accO[ds];                                            \
            _Pragma("unroll")                                                 \
            for (int r = 0; r < 16; ++r) o[r] *= corr;                        \
            accO[ds] = o;                                                     \
        }                                                                     \
    } else {                                                                  \
        l_run += ts;                                                          \
    }                                                                         \
    short8 pf[2];                                                             \
    _Pragma("unroll")                                                         \
    for (int ks = 0; ks < 2; ++ks) {                                          \
        unsigned a01 = cvt_pk(p_[8*ks+0], p_[8*ks+1]);                        \
        unsigned a23 = cvt_pk(p_[8*ks+2], p_[8*ks+3]);                        \
        unsigned b01 = cvt_pk(p_[8*ks+4], p_[8*ks+5]);                        \
        unsigned b23 = cvt_pk(p_[8*ks+6], p_[8*ks+7]);                        \
        unsigned ta01 = (unsigned)__shfl_xor((int)a01, 32);                   \
        unsigned ta23 = (unsigned)__shfl_xor((int)a23, 32);                   \
        unsigned tb01 = (unsigned)__shfl_xor((int)b01, 32);                   \
        unsigned tb23 = (unsigned)__shfl_xor((int)b23, 32);                   \
        union { unsigned u[4]; short8 v; } pu;                                \
        pu.u[0] = hi ? tb01 : a01;                                            \
        pu.u[1] = hi ? tb23 : a23;                                            \
        pu.u[2] = hi ? b01 : ta01;                                            \
        pu.u[3] = hi ? b23 : ta23;                                            \
        pf[ks] = pu.v;                                                        \
    }                                                                         \
    __builtin_amdgcn_s_setprio(1);                                            \
    _Pragma("unroll")                                                         \
    for (int ds = 0; ds < 4; ++ds)                                            \
        _Pragma("unroll")                                                     \
        for (int ks = 0; ks < 2; ++ks)                                        \
            accO[ds] = __builtin_amdgcn_mfma_f32_32x32x16_bf16(               \
                           vfc[ds * 2 + ks], pf[ks], accO[ds], 0, 0, 0);      \
    __builtin_amdgcn_s_setprio(0);                                            \
    if ((K) == 3) {                                                           \
        asm volatile("s_waitcnt lgkmcnt(0)" ::: "memory");                    \
        __builtin_amdgcn_s_barrier();                                         \
    }                                                                         \
}

    for (int g = 0; g < 4; ++g) {
        STEP_BODY(0, mA, mB)
        STEP_BODY(1, mB, mA)
        STEP_BODY(2, mA, mB)
        STEP_BODY(3, mB, mA)
    }
#undef STEP_BODY
#undef LOAD_KF
#undef LOAD_VF
#undef LOAD_MROWS
#undef PACK_MROWS

    // ---- wk-merge into UNNORMALIZED partials + (m,l). Ring is dead now.
    {
        float* mg = (float*)lds;
        const int slot = (wq * 64 + lane) * 68;
        if (wk == 1) {
            #pragma unroll
            for (int ds = 0; ds < 4; ++ds)
                #pragma unroll
                for (int rr = 0; rr < 4; ++rr) {
                    float4 v;
                    v.x = accO[ds][4*rr+0]; v.y = accO[ds][4*rr+1];
                    v.z = accO[ds][4*rr+2]; v.w = accO[ds][4*rr+3];
                    *(float4*)(mg + slot + ds * 16 + rr * 4) = v;
                }
            mg[slot + 64] = m_run;
            mg[slot + 65] = l_run;
        }
        __syncthreads();
        if (wk == 0) {
            float m1v = mg[slot + 64], l1 = mg[slot + 65];
            float m  = fmaxf(m_run, m1v);
            float f0 = ex2(m_run - m), f1 = ex2(m1v - m);
            float l  = l_run * f0 + l1 * f1;
            const int pair = b * 32 + qt;
            const int qrow = wq * 32 + lq;
            float* Op = OP + ((size_t)(pair * 2 + zh) * 64 + qrow) * 128;
            #pragma unroll
            for (int ds = 0; ds < 4; ++ds)
                #pragma unroll
                for (int rr = 0; rr < 4; ++rr) {
                    float4 part = *(const float4*)(mg + slot + ds * 16 + rr * 4);
                    float4 ov;
                    ov.x = accO[ds][4*rr+0] * f0 + part.x * f1;
                    ov.y = accO[ds][4*rr+1] * f0 + part.y * f1;
                    ov.z = accO[ds][4*rr+2] * f0 + part.z * f1;
                    ov.w = accO[ds][4*rr+3] * f0 + part.w * f1;
                    *(float4*)(Op + ds * 32 + 8 * rr + 4 * hi) = ov;
                }
            if (hi == 0) {
                float* mlp = ML + ((size_t)(pair * 2 + zh) * 64 + qrow) * 2;
                mlp[0] = m;
                mlp[1] = l;
            }
        }
    }
}

// ---- final merge of the two kv-half partials
__global__ __launch_bounds__(256) void merge_o(const float* __restrict__ OP,
                                               const float* __restrict__ ML,
                                               float* __restrict__ O)
{
    const int pair = blockIdx.x;            // b*32 + qt
    const int qt = pair & 31, b = pair >> 5;
    const int qrow = threadIdx.x >> 2;      // 64 rows, 4 threads each
    const int c0   = (threadIdx.x & 3) * 32;
    const float* mla = ML + ((size_t)(pair * 2 + 0) * 64 + qrow) * 2;
    const float* mlb = ML + ((size_t)(pair * 2 + 1) * 64 + qrow) * 2;
    float ma = mla[0], la = mla[1];
    float mb = mlb[0], lb = mlb[1];
    float m  = fmaxf(ma, mb);
    float fa = ex2(ma - m), fb = ex2(mb - m);
    float l  = la * fa + lb * fb;
    float inv = (l > 0.f) ? 1.f / l : 0.f;
    const float* Pa = OP + ((size_t)(pair * 2 + 0) * 64 + qrow) * 128 + c0;
    const float* Pb = OP + ((size_t)(pair * 2 + 1) * 64 + qrow) * 128 + c0;
    float* Ob = O + ((size_t)(b * S_LEN + qt * 64 + qrow)) * 128 + c0;
    #pragma unroll
    for (int j = 0; j < 8; ++j) {
        float4 a = *(const float4*)(Pa + 4 * j);
        float4 bv = *(const float4*)(Pb + 4 * j);
        float4 o;
        o.x = (a.x * fa + bv.x * fb) * inv;
        o.y = (a.y * fa + bv.y * fb) * inv;
        o.z = (a.z * fa + bv.z * fb) * inv;
        o.w = (a.w * fa + bv.w * fb) * inv;
        *(float4*)(Ob + 4 * j) = o;
    }
}

// ============================ mid kernel: the verified 113.5us kernel ============================
#define PM_OFF 34816
#define LDS_BYTES 45056

__global__ __launch_bounds__(256, 2)
void attn_fwd(const float* __restrict__ Q, const unsigned short* __restrict__ KF,
              const unsigned short* __restrict__ VF,
              const int* __restrict__ M,
              float* __restrict__ O)
{
    __shared__ __align__(128) char lds[LDS_BYTES];

    const int tid  = threadIdx.x;
    const int lane = tid & 63;
    const int w    = tid >> 6;
    const int wq   = w & 1;
    const int wk   = w >> 1;
    const int lq   = lane & 31;
    const int hi   = lane >> 5;
    const int qt   = blockIdx.x;
    const int b    = blockIdx.y;
    const int q0   = qt * BQ;

    short8 qf[8];
    {
        const float* qrow = Q + ((size_t)(b * S_LEN + q0 + wq * 32 + lq)) * DH;
        #pragma unroll
        for (int dsub = 0; dsub < 8; ++dsub) {
            const float* p = qrow + dsub * 16 + hi * 8;
            float4 a  = *(const float4*)(p);
            float4 bb = *(const float4*)(p + 4);
            short8 f;
            f[0] = f2b(a.x * SCALE2);  f[1] = f2b(a.y * SCALE2);
            f[2] = f2b(a.z * SCALE2);  f[3] = f2b(a.w * SCALE2);
            f[4] = f2b(bb.x * SCALE2); f[5] = f2b(bb.y * SCALE2);
            f[6] = f2b(bb.z * SCALE2); f[7] = f2b(bb.w * SCALE2);
            qf[dsub] = f;
        }
    }

    float m_run = -1e30f;
    float l_run = 0.f;
    floatx16 accO[4];
    #pragma unroll
    for (int i = 0; i < 4; ++i) accO[i] = (floatx16)(0.f);

    const unsigned short* KFl = KF + (((size_t)(b * 32) * 2 + wk) * 512
                                      + (size_t)hi * 32 + lq) * 8;
    const unsigned short* VFl = VF + ((((size_t)(b * 32) * 4 * 2 + wk) * 2) * 2 * 32
                                      + (size_t)hi * 32 + lq) * 8;

    const int* Mq = M + (size_t)b * S_LEN * S_LEN + (size_t)q0 * S_LEN;

    int4 mA[4], mB[4];
    short8 kfc[8], vfc[8];
    unsigned long long mgc[4];

#define LOAD_KF(T) {                                                          \
    const unsigned short* kp_ = KFl + (size_t)(T) * (2 * 512 * 8);            \
    _Pragma("unroll")                                                         \
    for (int dsub = 0; dsub < 8; ++dsub)                                      \
        kfc[dsub] = *(const short8*)(kp_ + dsub * 512);                       \
}
#define LOAD_VF(T) {                                                          \
    _Pragma("unroll")                                                         \
    for (int ds = 0; ds < 4; ++ds)                                            \
        _Pragma("unroll")                                                     \
        for (int ks = 0; ks < 2; ++ks)                                        \
            vfc[ds * 2 + ks] = *(const short8*)(VFl                           \
                + ((size_t)(T) * 16 + ds * 4 + ks) * (2 * 32 * 8));           \
}
#define LOAD_MROWS(DST, G, SB) {                                              \
    _Pragma("unroll")                                                         \
    for (int rr = 0; rr < 4; ++rr)                                            \
        DST[rr] = *(const int4*)(Mq + (size_t)(w * 16 + (SB) * 4 + rr) * S_LEN \
                                 + (G) * 256 + 4 * lane);                     \
}
#define PACK_MROWS(SRC, PBUF, SB) {                                           \
    char* pms_ = lds + PM_OFF + (PBUF) * 2560;                                \
    _Pragma("unroll")                                                         \
    for (int rr = 0; rr < 4; ++rr) {                                          \
        int4 mm = SRC[rr];                                                    \
        unsigned long long b0 = __ballot(mm.x != 0);                          \
        unsigned long long b1 = __ballot(mm.y != 0);                          \
        unsigned long long b2 = __ballot(mm.z != 0);                          \
        unsigned long long b3 = __ballot(mm.w != 0);                          \
        if (lane == 0) {                                                      \
            char* rp_ = pms_ + (w * 16 + (SB) * 4 + rr) * 40;                 \
            *(unsigned long long*)(rp_ +  0) = b0;                            \
            *(unsigned long long*)(rp_ +  8) = b1;                            \
            *(unsigned long long*)(rp_ + 16) = b2;                            \
            *(unsigned long long*)(rp_ + 24) = b3;                            \
        }                                                                     \
    }                                                                         \
}

    #pragma unroll
    for (int gg = 0; gg < 2; ++gg)
        #pragma unroll
        for (int sb = 0; sb < 4; ++sb) {
            int4 t_[4];
            LOAD_MROWS(t_, gg, sb)
            PACK_MROWS(t_, gg, sb)
        }
    __syncthreads();

#define STEP_BODY(T, TT, MCUR, MOLD) {                                        \
    LOAD_KF(T);                                                               \
    LOAD_VF(T);                                                               \
    if ((T) < 24) LOAD_MROWS(MCUR, ((T) >> 2) + 2, TT)                        \
    if ((T) >= 1 && (T) <= 24) {                                              \
        const int ps_   = ((T) - 1) & 3;                                      \
        const int pbuf_ = (((((T) - 1) >> 2) + 2) & 3);                       \
        PACK_MROWS(MOLD, pbuf_, ps_)                                          \
    }                                                                         \
    if ((TT) == 0) {                                                          \
        const char* pmb_ = lds + PM_OFF + (((T) >> 2) & 3) * 2560             \
                           + (wq * 32 + lq) * 40;                             \
        mgc[0] = *(const unsigned long long*)(pmb_ + 0);                      \
        mgc[1] = *(const unsigned long long*)(pmb_ + 8);                      \
        mgc[2] = *(const unsigned long long*)(pmb_ + 16);                     \
        mgc[3] = *(const unsigned long long*)(pmb_ + 24);                     \
    }                                                                         \
    floatx16 accS = (floatx16)(0.f);                                          \
    __builtin_amdgcn_s_setprio(1);                                            \
    _Pragma("unroll")                                                         \
    for (int dsub = 0; dsub < 8; ++dsub)                                      \
        accS = __builtin_amdgcn_mfma_f32_32x32x16_bf16(                       \
                   kfc[dsub], qf[dsub], accS, 0, 0, 0);                       \
    __builtin_amdgcn_s_setprio(0);                                            \
    const int base_ = (TT) * 16 + wk * 8 + hi;                                \
    unsigned mb0 = (unsigned)(mgc[0] >> base_);                               \
    unsigned mb1 = (unsigned)(mgc[1] >> base_);                               \
    unsigned mb2 = (unsigned)(mgc[2] >> base_);                               \
    unsigned mb3 = (unsigned)(mgc[3] >> base_);                               \
    float p_[16];                                                             \
    _Pragma("unroll")                                                         \
    for (int j = 0; j < 4; ++j) {                                             \
        p_[4*j+0] = ((mb0 >> (2*j)) & 1u) ? -1e30f : accS[4*j+0];             \
        p_[4*j+1] = ((mb1 >> (2*j)) & 1u) ? -1e30f : accS[4*j+1];             \
        p_[4*j+2] = ((mb2 >> (2*j)) & 1u) ? -1e30f : accS[4*j+2];             \
        p_[4*j+3] = ((mb3 >> (2*j)) & 1u) ? -1e30f : accS[4*j+3];             \
    }                                                                         \
    float mx = p_[0];                                                         \
    _Pragma("unroll")                                                         \
    for (int r = 1; r < 16; ++r) mx = fmaxf(mx, p_[r]);                       \
    mx = fmaxf(mx, __shfl_xor(mx, 32));                                       \
    int need = __any(mx - m_run > DTHR);                                      \
    float corr = 1.0f;                                                        \
    if (need) {                                                               \
        float mn = fmaxf(m_run, mx);                                          \
        corr = ex2(m_run - mn);                                               \
        m_run = mn;                                                           \
    }                                                                         \
    float ts = 0.f;                                                           \
    _Pragma("unroll")                                                         \
    for (int r = 0; r < 16; ++r) { p_[r] = ex2(p_[r] - m_run); ts += p_[r]; } \
    ts += __shfl_xor(ts, 32);                                                 \
    if (need) {                                                               \
        l_run = l_run * corr + ts;                                            \
        _Pragma("unroll")                                                     \
        for (int ds = 0; ds < 4; ++ds) {                                      \
            floatx16 o = accO[ds];                                            \
            _Pragma("unroll")                                                 \
            for (int r = 0; r < 16; ++r) o[r] *= corr;                        \
            accO[ds] = o;                                                     \
        }                                                                     \
    } else {                                                                  \
        l_run += ts;                                                          \
    }                                                                         \
    short8 pf[2];                                                             \
    _Pragma("unroll")                                                         \
    for (int ks = 0; ks < 2; ++ks) {                                          \
        unsigned a01 = cvt_pk(p_[8*ks+0], p_[8*ks+1]);                        \
        unsigned a23 = cvt_pk(p_[8*ks+2], p_[8*ks+3]);                        \
        unsigned b01 = cvt_pk(p_[8*ks+4], p_[8*ks+5]);                        \
        unsigned b23 = cvt_pk(p_[8*ks+6], p_[8*ks+7]);                        \
        unsigned ta01 = (unsigned)__shfl_xor((int)a01, 32);                   \
        unsigned ta23 = (unsigned)__shfl_xor((int)a23, 32);                   \
        unsigned tb01 = (unsigned)__shfl_xor((int)b01, 32);                   \
        unsigned tb23 = (unsigned)__shfl_xor((int)b23, 32);                   \
        union { unsigned u[4]; short8 v; } pu;                                \
        pu.u[0] = hi ? tb01 : a01;                                            \
        pu.u[1] = hi ? tb23 : a23;                                            \
        pu.u[2] = hi ? b01 : ta01;                                            \
        pu.u[3] = hi ? b23 : ta23;                                            \
        pf[ks] = pu.v;                                                        \
    }                                                                         \
    __builtin_amdgcn_s_setprio(1);                                            \
    _Pragma("unroll")                                                         \
    for (int ds = 0; ds < 4; ++ds)                                            \
        _Pragma("unroll")                                                     \
        for (int ks = 0; ks < 2; ++ks)                                        \
            accO[ds] = __builtin_amdgcn_mfma_f32_32x32x16_bf16(               \
                           vfc[ds * 2 + ks], pf[ks], accO[ds], 0, 0, 0);      \
    __builtin_amdgcn_s_setprio(0);                                            \
    if ((TT) == 3) {                                                          \
        asm volatile("s_waitcnt lgkmcnt(0)" ::: "memory");                    \
        __builtin_amdgcn_s_barrier();                                         \
    }                                                                         \
}

    for (int g = 0; g < 8; ++g) {
        STEP_BODY(4 * g + 0, 0, mA, mB)
        STEP_BODY(4 * g + 1, 1, mB, mA)
        STEP_BODY(4 * g + 2, 2, mA, mB)
        STEP_BODY(4 * g + 3, 3, mB, mA)
    }
#undef STEP_BODY
#undef LOAD_KF
#undef LOAD_VF
#undef LOAD_MROWS
#undef PACK_MROWS

    {
        float* mg = (float*)lds;
        const int slot = (wq * 64 + lane) * 68;
        if (wk == 1) {
            #pragma unroll
            for (int ds = 0; ds < 4; ++ds)
                #pragma unroll
                for (int rr = 0; rr < 4; ++rr) {
                    float4 v;
                    v.x = accO[ds][4*rr+0]; v.y = accO[ds][4*rr+1];
                    v.z = accO[ds][4*rr+2]; v.w = accO[ds][4*rr+3];
                    *(float4*)(mg + slot + ds * 16 + rr * 4) = v;
                }
            mg[slot + 64] = m_run;
            mg[slot + 65] = l_run;
        }
        __syncthreads();
        if (wk == 0) {
            float m1v = mg[slot + 64], l1 = mg[slot + 65];
            float m  = fmaxf(m_run, m1v);
            float f0 = ex2(m_run - m), f1 = ex2(m1v - m);
            float l  = l_run * f0 + l1 * f1;
            float inv = (l > 0.f) ? 1.f / l : 0.f;
            float* Ob = O + ((size_t)(b * S_LEN + q0 + wq * 32 + lq)) * DH;
            #pragma unroll
            for (int ds = 0; ds < 4; ++ds)
                #pragma unroll
                for (int rr = 0; rr < 4; ++rr) {
                    float4 part = *(const float4*)(mg + slot + ds * 16 + rr * 4);
                    float4 ov;
                    ov.x = (accO[ds][4*rr+0] * f0 + part.x * f1) * inv;
                    ov.y = (accO[ds][4*rr+1] * f0 + part.y * f1) * inv;
                    ov.z = (accO[ds][4*rr+2] * f0 + part.z * f1) * inv;
                    ov.w = (accO[ds][4*rr+3] * f0 + part.w * f1) * inv;
                    *(float4*)(Ob + ds * 32 + 8 * rr + 4 * hi) = ov;
                }
        }
    }
}

// ============================ fallback (verified round-3 kernel) ============================
#define FB_LDS_BYTES 77824

__global__ __launch_bounds__(256, 2)
void attn_fwd_fb(const float* __restrict__ Q, const float* __restrict__ K,
                 const float* __restrict__ V, const int* __restrict__ M,
                 float* __restrict__ O)
{
    __shared__ __align__(128) char lds[FB_LDS_BYTES];

    const int tid  = threadIdx.x;
    const int lane = tid & 63;
    const int w    = tid >> 6;
    const int c    = lane & 15;
    const int g    = lane >> 4;
    const int qt   = blockIdx.x;
    const int b    = blockIdx.y;
    const int q0   = qt * 64;

    const int rbase = tid >> 5;
    const int c4    = tid & 31;
    const unsigned swk = (unsigned)(c4 * 8) ^ (unsigned)(rbase << 4);
    const int vd    = tid & 127;
    const int vk0   = (tid >> 7) * 32;

    short8 qf[4];
    {
        const float* qrow = Q + ((size_t)(b * S_LEN + q0 + w * 16 + c)) * DH;
        #pragma unroll
        for (int dk = 0; dk < 4; ++dk) {
            const float* p = qrow + dk * 32 + g * 8;
            float4 a  = *(const float4*)(p);
            float4 bb = *(const float4*)(p + 4);
            short8 f;
            f[0] = f2b(a.x * SCALE);  f[1] = f2b(a.y * SCALE);
            f[2] = f2b(a.z * SCALE);  f[3] = f2b(a.w * SCALE);
            f[4] = f2b(bb.x * SCALE); f[5] = f2b(bb.y * SCALE);
            f[6] = f2b(bb.z * SCALE); f[7] = f2b(bb.w * SCALE);
            qf[dk] = f;
        }
    }

    float m_run[4] = {-1e30f, -1e30f, -1e30f, -1e30f};
    float l_run[4] = {0.f, 0.f, 0.f, 0.f};
    floatx4 accO[8];
    #pragma unroll
    for (int i = 0; i < 8; ++i) accO[i] = (floatx4)(0.f);

    const float* Kb = K + (size_t)b * S_LEN * DH;
    const float* Vb = V + (size_t)b * S_LEN * DH;
    const int*   Mb = M + (size_t)b * S_LEN * S_LEN + (size_t)q0 * S_LEN;

    size_t moff[4];
    #pragma unroll
    for (int r = 0; r < 4; ++r)
        moff[r] = (size_t)(w * 16 + 4 * g + r) * S_LEN;

    float4 kreg[8];
    float  vreg[32];
    int    mreg[16];

    #pragma unroll
    for (int i = 0; i < 8; ++i)
        kreg[i] = *(const float4*)(Kb + (size_t)(i * 8 + rbase) * DH + c4 * 4);
    #pragma unroll
    for (int j = 0; j < 32; ++j)
        vreg[j] = Vb[(size_t)(vk0 + j) * DH + vd];
    #pragma unroll
    for (int r = 0; r < 4; ++r)
        #pragma unroll
        for (int n = 0; n < 4; ++n)
            mreg[r * 4 + n] = Mb[moff[r] + n * 16 + c];

    #pragma unroll
    for (int i = 0; i < 8; ++i) {
        float4 kv = kreg[i];
        unsigned long long kp =
              (unsigned long long)f2b(kv.x)
            | ((unsigned long long)f2b(kv.y) << 16)
            | ((unsigned long long)f2b(kv.z) << 32)
            | ((unsigned long long)f2b(kv.w) << 48);
        *(unsigned long long*)(lds + (i * 8 + rbase) * 256 + swk) = kp;
    }
    {
        char* vbase = lds + 32768 + vd * 144 + vk0 * 2;
        #pragma unroll
        for (int i = 0; i < 4; ++i) {
            short8 pk;
            #pragma unroll
            for (int e = 0; e < 8; ++e) pk[e] = f2b(vreg[i * 8 + e]);
            *(short8*)(vbase + i * 16) = pk;
        }
    }
    #pragma unroll
    for (int i = 0; i < 8; ++i)
        kreg[i] = *(const float4*)(Kb + (size_t)(BKV + i * 8 + rbase) * DH + c4 * 4);
    #pragma unroll
    for (int j = 0; j < 32; ++j)
        vreg[j] = Vb[(size_t)(BKV + vk0 + j) * DH + vd];

    __syncthreads();

    char* psw = lds + 69632 + w * 2048;

    for (int step = 0; step < NSTEP; ++step) {
        const int p = step & 1;
        const int kv0 = step * BKV;
        char* KHp = lds + p * 16384;
        char* VTp = lds + 32768 + p * 18432;

        floatx4 accS[4];
        #pragma unroll
        for (int n = 0; n < 4; ++n) accS[n] = (floatx4)(0.f);
        #pragma unroll
        for (int n = 0; n < 4; ++n) {
            const char* krow = KHp + (n * 16 + c) * 256;
            #pragma unroll
            for (int dk = 0; dk < 4; ++dk) {
                unsigned colb = (unsigned)(dk * 64 + g * 16) ^ (unsigned)((c & 7) << 4);
                short8 kf = *(const short8*)(krow + colb);
                accS[n] = __builtin_amdgcn_mfma_f32_16x16x32_bf16(qf[dk], kf, accS[n], 0, 0, 0);
            }
        }

        float pv[4][4];
        float corr[4];
        #pragma unroll
        for (int r = 0; r < 4; ++r) {
            float sv[4];
            #pragma unroll
            for (int n = 0; n < 4; ++n) {
                float s = accS[n][r];
                if (mreg[r * 4 + n]) s = -1e30f;
                sv[n] = s;
            }
            float tm = fmaxf(fmaxf(sv[0], sv[1]), fmaxf(sv[2], sv[3]));
            #pragma unroll
            for (int off = 1; off < 16; off <<= 1)
                tm = fmaxf(tm, __shfl_xor(tm, off, 64));
            float mn = fmaxf(m_run[r], tm);
            corr[r]  = __expf(m_run[r] - mn);
            m_run[r] = mn;
            float ts = 0.f;
            #pragma unroll
            for (int n = 0; n < 4; ++n) { pv[n][r] = __expf(sv[n] - mn); ts += pv[n][r]; }
            #pragma unroll
            for (int off = 1; off < 16; off <<= 1)
                ts += __shfl_xor(ts, off, 64);
            l_run[r] = l_run[r] * corr[r] + ts;
        }
        if (step + 1 < NSTEP) {
            const int kvn = kv0 + BKV;
            #pragma unroll
            for (int r = 0; r < 4; ++r)
                #pragma unroll
                for (int n = 0; n < 4; ++n)
                    mreg[r * 4 + n] = Mb[moff[r] + kvn + n * 16 + c];
        }

        #pragma unroll
        for (int s8 = 0; s8 < 8; ++s8) {
            floatx4 o = accO[s8];
            o[0] *= corr[0]; o[1] *= corr[1]; o[2] *= corr[2]; o[3] *= corr[3];
            accO[s8] = o;
        }

        #pragma unroll
        for (int r = 0; r < 4; ++r) {
            int rl = 4 * g + r;
            #pragma unroll
            for (int n = 0; n < 4; ++n) {
                unsigned colb = (unsigned)((n * 16 + c) * 2) ^ (unsigned)((rl & 7) << 4);
                *(unsigned short*)(psw + rl * 128 + colb) = f2b(pv[n][r]);
            }
        }

        #pragma unroll
        for (int sub = 0; sub < 2; ++sub) {
            unsigned colb = (unsigned)(sub * 64 + g * 16) ^ (unsigned)((c & 7) << 4);
            short8 pf = *(const short8*)(psw + c * 128 + colb);
            #pragma unroll
            for (int s8 = 0; s8 < 8; ++s8) {
                short8 vf = *(const short8*)(VTp + (s8 * 16 + c) * 144 + sub * 64 + g * 16);
                accO[s8] = __builtin_amdgcn_mfma_f32_16x16x32_bf16(pf, vf, accO[s8], 0, 0, 0);
            }
        }

        if (step + 1 < NSTEP) {
            char* KHn = lds + (p ^ 1) * 16384;
            char* VTn = lds + 32768 + (p ^ 1) * 18432;
            #pragma unroll
            for (int i = 0; i < 8; ++i) {
                float4 kv = kreg[i];
                unsigned long long kp =
                      (unsigned long long)f2b(kv.x)
                    | ((unsigned long long)f2b(kv.y) << 16)
                    | ((unsigned long long)f2b(kv.z) << 32)
                    | ((unsigned long long)f2b(kv.w) << 48);
                *(unsigned long long*)(KHn + (i * 8 + rbase) * 256 + swk) = kp;
            }
            char* vbase = VTn + vd * 144 + vk0 * 2;
            #pragma unroll
            for (int i = 0; i < 4; ++i) {
                short8 pk;
                #pragma unroll
                for (int e = 0; e < 8; ++e) pk[e] = f2b(vreg[i * 8 + e]);
                *(short8*)(vbase + i * 16) = pk;
            }
            if (step + 2 < NSTEP) {
                const int kvn2 = kv0 + 2 * BKV;
                #pragma unroll
                for (int i = 0; i < 8; ++i)
                    kreg[i] = *(const float4*)(Kb + (size_t)(kvn2 + i * 8 + rbase) * DH + c4 * 4);
                #pragma unroll
                for (int j = 0; j < 32; ++j)
                    vreg[j] = Vb[(size_t)(kvn2 + vk0 + j) * DH + vd];
            }
        }
        __syncthreads();
    }

    float inv[4];
    #pragma unroll
    for (int r = 0; r < 4; ++r) inv[r] = (l_run[r] > 0.f) ? 1.f / l_run[r] : 0.f;
    float* Ob = O + ((size_t)(b * S_LEN + q0 + w * 16)) * DH;
    #pragma unroll
    for (int s8 = 0; s8 < 8; ++s8) {
        #pragma unroll
        for (int r = 0; r < 4; ++r) {
            Ob[(size_t)(4 * g + r) * DH + s8 * 16 + c] = accO[s8][r] * inv[r];
        }
    }
}

extern "C" void kernel_launch(void* const* d_in, const int* in_sizes, int n_in,
                              void* d_out, int out_size, void* d_ws, size_t ws_size,
                              hipStream_t stream) {
    const float* Q = (const float*)d_in[0];
    const float* K = (const float*)d_in[1];
    const float* V = (const float*)d_in[2];
    const int*   M = (const int*)d_in[3];
    float*       O = (float*)d_out;

    const size_t elems    = (size_t)16 * S_LEN * DH;
    const size_t kv_bytes = elems * sizeof(unsigned short);          // 8.39 MB each
    const size_t op_bytes = (size_t)1024 * 64 * 128 * sizeof(float); // 33.55 MB
    const size_t ml_bytes = (size_t)1024 * 64 * 2 * sizeof(float);   // 0.52 MB

    if (ws_size >= 2 * kv_bytes + op_bytes + ml_bytes) {
        unsigned short* KFp = (unsigned short*)d_ws;
        unsigned short* VFp = (unsigned short*)d_ws + elems;
        float* OP = (float*)((char*)d_ws + 2 * kv_bytes);
        float* ML = (float*)((char*)d_ws + 2 * kv_bytes + op_bytes);
        kfrag_make<<<dim3(32, 16), dim3(256), 0, stream>>>(K, KFp);
        vfrag_make<<<dim3(S_LEN / 32, DH / 32, 16), dim3(256), 0, stream>>>(V, VFp);
        attn_split<<<dim3(S_LEN / BQ, 16, 2), dim3(256), 0, stream>>>(Q, KFp, VFp, M, OP, ML);
        merge_o<<<dim3(512), dim3(256), 0, stream>>>(OP, ML, O);
    } else if (ws_size >= 2 * kv_bytes) {
        unsigned short* KFp = (unsigned short*)d_ws;
        unsigned short* VFp = (unsigned short*)d_ws + elems;
        kfrag_make<<<dim3(32, 16), dim3(256), 0, stream>>>(K, KFp);
        vfrag_make<<<dim3(S_LEN / 32, DH / 32, 16), dim3(256), 0, stream>>>(V, VFp);
        attn_fwd<<<dim3(S_LEN / BQ, 16), dim3(256), 0, stream>>>(Q, KFp, VFp, M, O);
    } else {
        attn_fwd_fb<<<dim3(S_LEN / 64, 16), dim3(256), 0, stream>>>(Q, K, V, M, O);
    }
}

// Round 19
// 113.275 us; speedup vs baseline: 3.5484x; 1.5065x over previous
//
#include <hip/hip_runtime.h>
#include <hip/hip_bf16.h>
#include <stdint.h>

typedef __attribute__((ext_vector_type(8)))  short short8;
typedef __attribute__((ext_vector_type(4)))  float floatx4;
typedef __attribute__((ext_vector_type(16))) float floatx16;

#define S_LEN 2048
#define DH    128
#define BQ    64
#define BKV   64
#define NSTEP (S_LEN / BKV)
#define SCALE 0.08838834764831845f                  // 1/sqrt(128)
#define SCALE2 0.12753785429791905f                 // SCALE * log2(e)
#define DTHR 11.541560327111708f                    // 8 * log2(e)

__device__ __forceinline__ float ex2(float x) { return __builtin_amdgcn_exp2f(x); }

__device__ __forceinline__ unsigned short f2b(float f) {
    union { float f; unsigned u; } v; v.f = f;
    unsigned r = v.u + 0x7fffu + ((v.u >> 16) & 1u);
    return (unsigned short)(r >> 16);
}

__device__ __forceinline__ unsigned cvt_pk(float lo, float hi) {
    unsigned r;
    asm("v_cvt_pk_bf16_f32 %0, %1, %2" : "=v"(r) : "v"(lo), "v"(hi));
    return r;
}

// ============================ prepass kernels ============================

// K fragment-major (verified R13-R15): frag F=(wk,dsub,hi,lq) of tile (b,T)
// holds K[b][kv=T*64+wk*32+lq][d=dsub*16+hi*8 .. +8] as 8 bf16.
__global__ __launch_bounds__(256) void kfrag_make(const float* __restrict__ K,
                                                  unsigned short* __restrict__ KF)
{
    const int T = blockIdx.x, b = blockIdx.y;
    const float* Kb = K + ((size_t)b * S_LEN + T * 64) * DH;
    unsigned short* out = KF + ((size_t)(b * 32 + T)) * 1024 * 8;
    #pragma unroll
    for (int i = 0; i < 4; ++i) {
        int F = i * 256 + threadIdx.x;
        int lq = F & 31, h = (F >> 5) & 1, dsub = (F >> 6) & 7, wk = F >> 9;
        const float* src = Kb + (size_t)(wk * 32 + lq) * DH + dsub * 16 + h * 8;
        float4 a = *(const float4*)src, bb = *(const float4*)(src + 4);
        short8 f;
        f[0] = f2b(a.x);  f[1] = f2b(a.y);  f[2] = f2b(a.z);  f[3] = f2b(a.w);
        f[4] = f2b(bb.x); f[5] = f2b(bb.y); f[6] = f2b(bb.z); f[7] = f2b(bb.w);
        *(short8*)(out + (size_t)F * 8) = f;
    }
}

// V fragment-major (verified R13-R15): frag (b,T,ds,wk,ks,hi,lq) holds
// V[b][kv=T*64+wk*32+ks*16+hi*8+e][d=ds*32+lq] transposed.
__global__ __launch_bounds__(256) void vfrag_make(const float* __restrict__ V,
                                                  unsigned short* __restrict__ VF)
{
    __shared__ float t[32][33];
    const int k0 = blockIdx.x * 32, d0 = blockIdx.y * 32, b = blockIdx.z;
    const int tx = threadIdx.x & 31, ty = threadIdx.x >> 5;
    const float* Vb = V + ((size_t)b * S_LEN + k0) * DH + d0;
    #pragma unroll
    for (int i = 0; i < 4; ++i)
        t[ty + 8 * i][tx] = Vb[(size_t)(ty + 8 * i) * DH + tx];
    __syncthreads();
    if (threadIdx.x < 128) {
        const int lq = threadIdx.x & 31;
        const int h  = (threadIdx.x >> 5) & 1;
        const int ks = threadIdx.x >> 6;
        const int T = k0 >> 6, wk = (k0 >> 5) & 1, ds = d0 >> 5;
        short8 f;
        #pragma unroll
        for (int e = 0; e < 8; ++e)
            f[e] = f2b(t[ks * 16 + h * 8 + e][lq]);
        unsigned short* o = VF +
            ((((((size_t)(b * 32 + T) * 4 + ds) * 2 + wk) * 2 + ks) * 2 + h) * 32 + lq) * 8;
        *(short8*)o = f;
    }
}

// ============================ main kernel ============================
// Fragment-major K/V from global (L2); mask ballot-packed IN-KERNEL, 2 groups
// (8 steps) ahead: per-row contiguous int4 loads (1KB/instr), ballots one
// step later, 4-deep LDS ring. One raw s_barrier per group (no vmcnt drain).
// 32x32 MFMA; waves (wq,wk); in-reg P exchange; per-wave (m,l); end merge.
// LDS: merge 0..34816; packed-mask ring 34816..45056 (4 bufs x 64 rows x 40B)
#define PM_OFF 34816
#define LDS_BYTES 45056

__global__ __launch_bounds__(256, 2)
void attn_fwd(const float* __restrict__ Q, const unsigned short* __restrict__ KF,
              const unsigned short* __restrict__ VF,
              const int* __restrict__ M,
              float* __restrict__ O)
{
    __shared__ __align__(128) char lds[LDS_BYTES];

    const int tid  = threadIdx.x;
    const int lane = tid & 63;
    const int w    = tid >> 6;
    const int wq   = w & 1;
    const int wk   = w >> 1;
    const int lq   = lane & 31;
    const int hi   = lane >> 5;
    const int qt   = blockIdx.x;
    const int b    = blockIdx.y;
    const int q0   = qt * BQ;

    // ---- Q B-fragments (scale*log2e folded)
    short8 qf[8];
    {
        const float* qrow = Q + ((size_t)(b * S_LEN + q0 + wq * 32 + lq)) * DH;
        #pragma unroll
        for (int dsub = 0; dsub < 8; ++dsub) {
            const float* p = qrow + dsub * 16 + hi * 8;
            float4 a  = *(const float4*)(p);
            float4 bb = *(const float4*)(p + 4);
            short8 f;
            f[0] = f2b(a.x * SCALE2);  f[1] = f2b(a.y * SCALE2);
            f[2] = f2b(a.z * SCALE2);  f[3] = f2b(a.w * SCALE2);
            f[4] = f2b(bb.x * SCALE2); f[5] = f2b(bb.y * SCALE2);
            f[6] = f2b(bb.z * SCALE2); f[7] = f2b(bb.w * SCALE2);
            qf[dsub] = f;
        }
    }

    float m_run = -1e30f;
    float l_run = 0.f;
    floatx16 accO[4];
    #pragma unroll
    for (int i = 0; i < 4; ++i) accO[i] = (floatx16)(0.f);

    const unsigned short* KFl = KF + (((size_t)(b * 32) * 2 + wk) * 512
                                      + (size_t)hi * 32 + lq) * 8;
    const unsigned short* VFl = VF + ((((size_t)(b * 32) * 4 * 2 + wk) * 2) * 2 * 32
                                      + (size_t)hi * 32 + lq) * 8;

    // block mask base: rows are block-local q rows 0..63
    const int* Mq = M + (size_t)b * S_LEN * S_LEN + (size_t)q0 * S_LEN;

    int4 mA[4], mB[4];
    short8 kfc[8], vfc[8];
    unsigned long long mgc[4];

#define LOAD_KF(T) {                                                          \
    const unsigned short* kp_ = KFl + (size_t)(T) * (2 * 512 * 8);            \
    _Pragma("unroll")                                                         \
    for (int dsub = 0; dsub < 8; ++dsub)                                      \
        kfc[dsub] = *(const short8*)(kp_ + dsub * 512);                       \
}

#define LOAD_VF(T) {                                                          \
    _Pragma("unroll")                                                         \
    for (int ds = 0; ds < 4; ++ds)                                            \
        _Pragma("unroll")                                                     \
        for (int ks = 0; ks < 2; ++ks)                                        \
            vfc[ds * 2 + ks] = *(const short8*)(VFl                           \
                + ((size_t)(T) * 16 + ds * 4 + ks) * (2 * 32 * 8));           \
}

    // load 4 mask rows (per-row contiguous 1KB/instr) for group G, sub s
#define LOAD_MROWS(DST, G, SB) {                                              \
    _Pragma("unroll")                                                         \
    for (int rr = 0; rr < 4; ++rr)                                            \
        DST[rr] = *(const int4*)(Mq + (size_t)(w * 16 + (SB) * 4 + rr) * S_LEN \
                                 + (G) * 256 + 4 * lane);                     \
}
    // ballot+store 4 rows into LDS ring buffer PBUF, rows of sub SB
#define PACK_MROWS(SRC, PBUF, SB) {                                           \
    char* pms_ = lds + PM_OFF + (PBUF) * 2560;                                \
    _Pragma("unroll")                                                         \
    for (int rr = 0; rr < 4; ++rr) {                                          \
        int4 mm = SRC[rr];                                                    \
        unsigned long long b0 = __ballot(mm.x != 0);                          \
        unsigned long long b1 = __ballot(mm.y != 0);                          \
        unsigned long long b2 = __ballot(mm.z != 0);                          \
        unsigned long long b3 = __ballot(mm.w != 0);                          \
        if (lane == 0) {                                                      \
            char* rp_ = pms_ + (w * 16 + (SB) * 4 + rr) * 40;                 \
            *(unsigned long long*)(rp_ +  0) = b0;                            \
            *(unsigned long long*)(rp_ +  8) = b1;                            \
            *(unsigned long long*)(rp_ + 16) = b2;                            \
            *(unsigned long long*)(rp_ + 24) = b3;                            \
        }                                                                     \
    }                                                                         \
}

    // ---- prologue: pack groups 0 and 1 directly
    #pragma unroll
    for (int gg = 0; gg < 2; ++gg)
        #pragma unroll
        for (int sb = 0; sb < 4; ++sb) {
            int4 t_[4];
            LOAD_MROWS(t_, gg, sb)
            PACK_MROWS(t_, gg, sb)
        }
    __syncthreads();

#define STEP_BODY(T, TT, MCUR, MOLD) {                                        \
    LOAD_KF(T);                                                               \
    LOAD_VF(T);                                                               \
    /* mask loads for group (T>>2)+2, sub TT (in flight ~1 step) */           \
    if ((T) < 24) LOAD_MROWS(MCUR, ((T) >> 2) + 2, TT)                        \
    /* ballot+store batch loaded last step */                                 \
    if ((T) >= 1 && (T) <= 24) {                                              \
        const int ps_   = ((T) - 1) & 3;                                      \
        const int pbuf_ = (((((T) - 1) >> 2) + 2) & 3);                       \
        PACK_MROWS(MOLD, pbuf_, ps_)                                          \
    }                                                                         \
    /* group start: fetch this group's packed words from LDS */               \
    if ((TT) == 0) {                                                          \
        const char* pmb_ = lds + PM_OFF + (((T) >> 2) & 3) * 2560             \
                           + (wq * 32 + lq) * 40;                             \
        mgc[0] = *(const unsigned long long*)(pmb_ + 0);                      \
        mgc[1] = *(const unsigned long long*)(pmb_ + 8);                      \
        mgc[2] = *(const unsigned long long*)(pmb_ + 16);                     \
        mgc[3] = *(const unsigned long long*)(pmb_ + 24);                     \
    }                                                                         \
    /* QK^T */                                                                \
    floatx16 accS = (floatx16)(0.f);                                          \
    __builtin_amdgcn_s_setprio(1);                                            \
    _Pragma("unroll")                                                         \
    for (int dsub = 0; dsub < 8; ++dsub)                                      \
        accS = __builtin_amdgcn_mfma_f32_32x32x16_bf16(                       \
                   kfc[dsub], qf[dsub], accS, 0, 0, 0);                       \
    __builtin_amdgcn_s_setprio(0);                                            \
    /* softmax with packed mask bits (verified R13 mapping) */                \
    const int base_ = (TT) * 16 + wk * 8 + hi;                                \
    unsigned mb0 = (unsigned)(mgc[0] >> base_);                               \
    unsigned mb1 = (unsigned)(mgc[1] >> base_);                               \
    unsigned mb2 = (unsigned)(mgc[2] >> base_);                               \
    unsigned mb3 = (unsigned)(mgc[3] >> base_);                               \
    float p_[16];                                                             \
    _Pragma("unroll")                                                         \
    for (int j = 0; j < 4; ++j) {                                             \
        p_[4*j+0] = ((mb0 >> (2*j)) & 1u) ? -1e30f : accS[4*j+0];             \
        p_[4*j+1] = ((mb1 >> (2*j)) & 1u) ? -1e30f : accS[4*j+1];             \
        p_[4*j+2] = ((mb2 >> (2*j)) & 1u) ? -1e30f : accS[4*j+2];             \
        p_[4*j+3] = ((mb3 >> (2*j)) & 1u) ? -1e30f : accS[4*j+3];             \
    }                                                                         \
    float mx = p_[0];                                                         \
    _Pragma("unroll")                                                         \
    for (int r = 1; r < 16; ++r) mx = fmaxf(mx, p_[r]);                       \
    mx = fmaxf(mx, __shfl_xor(mx, 32));                                       \
    int need = __any(mx - m_run > DTHR);                                      \
    float corr = 1.0f;                                                        \
    if (need) {                                                               \
        float mn = fmaxf(m_run, mx);                                          \
        corr = ex2(m_run - mn);                                               \
        m_run = mn;                                                           \
    }                                                                         \
    float ts = 0.f;                                                           \
    _Pragma("unroll")                                                         \
    for (int r = 0; r < 16; ++r) { p_[r] = ex2(p_[r] - m_run); ts += p_[r]; } \
    ts += __shfl_xor(ts, 32);                                                 \
    if (need) {                                                               \
        l_run = l_run * corr + ts;                                            \
        _Pragma("unroll")                                                     \
        for (int ds = 0; ds < 4; ++ds) {                                      \
            floatx16 o = accO[ds];                                            \
            _Pragma("unroll")                                                 \
            for (int r = 0; r < 16; ++r) o[r] *= corr;                        \
            accO[ds] = o;                                                     \
        }                                                                     \
    } else {                                                                  \
        l_run += ts;                                                          \
    }                                                                         \
    /* P B-frags via in-register half exchange */                             \
    short8 pf[2];                                                             \
    _Pragma("unroll")                                                         \
    for (int ks = 0; ks < 2; ++ks) {                                          \
        unsigned a01 = cvt_pk(p_[8*ks+0], p_[8*ks+1]);                        \
        unsigned a23 = cvt_pk(p_[8*ks+2], p_[8*ks+3]);                        \
        unsigned b01 = cvt_pk(p_[8*ks+4], p_[8*ks+5]);                        \
        unsigned b23 = cvt_pk(p_[8*ks+6], p_[8*ks+7]);                        \
        unsigned ta01 = (unsigned)__shfl_xor((int)a01, 32);                   \
        unsigned ta23 = (unsigned)__shfl_xor((int)a23, 32);                   \
        unsigned tb01 = (unsigned)__shfl_xor((int)b01, 32);                   \
        unsigned tb23 = (unsigned)__shfl_xor((int)b23, 32);                   \
        union { unsigned u[4]; short8 v; } pu;                                \
        pu.u[0] = hi ? tb01 : a01;                                            \
        pu.u[1] = hi ? tb23 : a23;                                            \
        pu.u[2] = hi ? b01 : ta01;                                            \
        pu.u[3] = hi ? b23 : ta23;                                            \
        pf[ks] = pu.v;                                                        \
    }                                                                         \
    /* PV */                                                                  \
    __builtin_amdgcn_s_setprio(1);                                            \
    _Pragma("unroll")                                                         \
    for (int ds = 0; ds < 4; ++ds)                                            \
        _Pragma("unroll")                                                     \
        for (int ks = 0; ks < 2; ++ks)                                        \
            accO[ds] = __builtin_amdgcn_mfma_f32_32x32x16_bf16(               \
                           vfc[ds * 2 + ks], pf[ks], accO[ds], 0, 0, 0);      \
    __builtin_amdgcn_s_setprio(0);                                            \
    /* group boundary: LDS-only barrier (mask loads stay in flight) */        \
    if ((TT) == 3) {                                                          \
        asm volatile("s_waitcnt lgkmcnt(0)" ::: "memory");                    \
        __builtin_amdgcn_s_barrier();                                         \
    }                                                                         \
}

    for (int g = 0; g < 8; ++g) {
        STEP_BODY(4 * g + 0, 0, mA, mB)
        STEP_BODY(4 * g + 1, 1, mB, mA)
        STEP_BODY(4 * g + 2, 2, mA, mB)
        STEP_BODY(4 * g + 3, 3, mB, mA)
    }
#undef STEP_BODY
#undef LOAD_KF
#undef LOAD_VF
#undef LOAD_MROWS
#undef PACK_MROWS

    // ---- merge partials across wk pairs (loop ended on barrier)
    {
        float* mg = (float*)lds;
        const int slot = (wq * 64 + lane) * 68;
        if (wk == 1) {
            #pragma unroll
            for (int ds = 0; ds < 4; ++ds)
                #pragma unroll
                for (int rr = 0; rr < 4; ++rr) {
                    float4 v;
                    v.x = accO[ds][4*rr+0]; v.y = accO[ds][4*rr+1];
                    v.z = accO[ds][4*rr+2]; v.w = accO[ds][4*rr+3];
                    *(float4*)(mg + slot + ds * 16 + rr * 4) = v;
                }
            mg[slot + 64] = m_run;
            mg[slot + 65] = l_run;
        }
        __syncthreads();
        if (wk == 0) {
            float m1 = mg[slot + 64], l1 = mg[slot + 65];
            float m  = fmaxf(m_run, m1);
            float f0 = ex2(m_run - m), f1 = ex2(m1 - m);
            float l  = l_run * f0 + l1 * f1;
            float inv = (l > 0.f) ? 1.f / l : 0.f;
            float* Ob = O + ((size_t)(b * S_LEN + q0 + wq * 32 + lq)) * DH;
            #pragma unroll
            for (int ds = 0; ds < 4; ++ds)
                #pragma unroll
                for (int rr = 0; rr < 4; ++rr) {
                    float4 part = *(const float4*)(mg + slot + ds * 16 + rr * 4);
                    float4 ov;
                    ov.x = (accO[ds][4*rr+0] * f0 + part.x * f1) * inv;
                    ov.y = (accO[ds][4*rr+1] * f0 + part.y * f1) * inv;
                    ov.z = (accO[ds][4*rr+2] * f0 + part.z * f1) * inv;
                    ov.w = (accO[ds][4*rr+3] * f0 + part.w * f1) * inv;
                    *(float4*)(Ob + ds * 32 + 8 * rr + 4 * hi) = ov;
                }
        }
    }
}

// ============================ fallback (verified round-3 kernel) ============================
#define FB_LDS_BYTES 77824

__global__ __launch_bounds__(256, 2)
void attn_fwd_fb(const float* __restrict__ Q, const float* __restrict__ K,
                 const float* __restrict__ V, const int* __restrict__ M,
                 float* __restrict__ O)
{
    __shared__ __align__(128) char lds[FB_LDS_BYTES];

    const int tid  = threadIdx.x;
    const int lane = tid & 63;
    const int w    = tid >> 6;
    const int c    = lane & 15;
    const int g    = lane >> 4;
    const int qt   = blockIdx.x;
    const int b    = blockIdx.y;
    const int q0   = qt * 64;

    const int rbase = tid >> 5;
    const int c4    = tid & 31;
    const unsigned swk = (unsigned)(c4 * 8) ^ (unsigned)(rbase << 4);
    const int vd    = tid & 127;
    const int vk0   = (tid >> 7) * 32;

    short8 qf[4];
    {
        const float* qrow = Q + ((size_t)(b * S_LEN + q0 + w * 16 + c)) * DH;
        #pragma unroll
        for (int dk = 0; dk < 4; ++dk) {
            const float* p = qrow + dk * 32 + g * 8;
            float4 a  = *(const float4*)(p);
            float4 bb = *(const float4*)(p + 4);
            short8 f;
            f[0] = f2b(a.x * SCALE);  f[1] = f2b(a.y * SCALE);
            f[2] = f2b(a.z * SCALE);  f[3] = f2b(a.w * SCALE);
            f[4] = f2b(bb.x * SCALE); f[5] = f2b(bb.y * SCALE);
            f[6] = f2b(bb.z * SCALE); f[7] = f2b(bb.w * SCALE);
            qf[dk] = f;
        }
    }

    float m_run[4] = {-1e30f, -1e30f, -1e30f, -1e30f};
    float l_run[4] = {0.f, 0.f, 0.f, 0.f};
    floatx4 accO[8];
    #pragma unroll
    for (int i = 0; i < 8; ++i) accO[i] = (floatx4)(0.f);

    const float* Kb = K + (size_t)b * S_LEN * DH;
    const float* Vb = V + (size_t)b * S_LEN * DH;
    const int*   Mb = M + (size_t)b * S_LEN * S_LEN + (size_t)q0 * S_LEN;

    size_t moff[4];
    #pragma unroll
    for (int r = 0; r < 4; ++r)
        moff[r] = (size_t)(w * 16 + 4 * g + r) * S_LEN;

    float4 kreg[8];
    float  vreg[32];
    int    mreg[16];

    #pragma unroll
    for (int i = 0; i < 8; ++i)
        kreg[i] = *(const float4*)(Kb + (size_t)(i * 8 + rbase) * DH + c4 * 4);
    #pragma unroll
    for (int j = 0; j < 32; ++j)
        vreg[j] = Vb[(size_t)(vk0 + j) * DH + vd];
    #pragma unroll
    for (int r = 0; r < 4; ++r)
        #pragma unroll
        for (int n = 0; n < 4; ++n)
            mreg[r * 4 + n] = Mb[moff[r] + n * 16 + c];

    #pragma unroll
    for (int i = 0; i < 8; ++i) {
        float4 kv = kreg[i];
        unsigned long long kp =
              (unsigned long long)f2b(kv.x)
            | ((unsigned long long)f2b(kv.y) << 16)
            | ((unsigned long long)f2b(kv.z) << 32)
            | ((unsigned long long)f2b(kv.w) << 48);
        *(unsigned long long*)(lds + (i * 8 + rbase) * 256 + swk) = kp;
    }
    {
        char* vbase = lds + 32768 + vd * 144 + vk0 * 2;
        #pragma unroll
        for (int i = 0; i < 4; ++i) {
            short8 pk;
            #pragma unroll
            for (int e = 0; e < 8; ++e) pk[e] = f2b(vreg[i * 8 + e]);
            *(short8*)(vbase + i * 16) = pk;
        }
    }
    #pragma unroll
    for (int i = 0; i < 8; ++i)
        kreg[i] = *(const float4*)(Kb + (size_t)(BKV + i * 8 + rbase) * DH + c4 * 4);
    #pragma unroll
    for (int j = 0; j < 32; ++j)
        vreg[j] = Vb[(size_t)(BKV + vk0 + j) * DH + vd];

    __syncthreads();

    char* psw = lds + 69632 + w * 2048;

    for (int step = 0; step < NSTEP; ++step) {
        const int p = step & 1;
        const int kv0 = step * BKV;
        char* KHp = lds + p * 16384;
        char* VTp = lds + 32768 + p * 18432;

        floatx4 accS[4];
        #pragma unroll
        for (int n = 0; n < 4; ++n) accS[n] = (floatx4)(0.f);
        #pragma unroll
        for (int n = 0; n < 4; ++n) {
            const char* krow = KHp + (n * 16 + c) * 256;
            #pragma unroll
            for (int dk = 0; dk < 4; ++dk) {
                unsigned colb = (unsigned)(dk * 64 + g * 16) ^ (unsigned)((c & 7) << 4);
                short8 kf = *(const short8*)(krow + colb);
                accS[n] = __builtin_amdgcn_mfma_f32_16x16x32_bf16(qf[dk], kf, accS[n], 0, 0, 0);
            }
        }

        float pv[4][4];
        float corr[4];
        #pragma unroll
        for (int r = 0; r < 4; ++r) {
            float sv[4];
            #pragma unroll
            for (int n = 0; n < 4; ++n) {
                float s = accS[n][r];
                if (mreg[r * 4 + n]) s = -1e30f;
                sv[n] = s;
            }
            float tm = fmaxf(fmaxf(sv[0], sv[1]), fmaxf(sv[2], sv[3]));
            #pragma unroll
            for (int off = 1; off < 16; off <<= 1)
                tm = fmaxf(tm, __shfl_xor(tm, off, 64));
            float mn = fmaxf(m_run[r], tm);
            corr[r]  = __expf(m_run[r] - mn);
            m_run[r] = mn;
            float ts = 0.f;
            #pragma unroll
            for (int n = 0; n < 4; ++n) { pv[n][r] = __expf(sv[n] - mn); ts += pv[n][r]; }
            #pragma unroll
            for (int off = 1; off < 16; off <<= 1)
                ts += __shfl_xor(ts, off, 64);
            l_run[r] = l_run[r] * corr[r] + ts;
        }
        if (step + 1 < NSTEP) {
            const int kvn = kv0 + BKV;
            #pragma unroll
            for (int r = 0; r < 4; ++r)
                #pragma unroll
                for (int n = 0; n < 4; ++n)
                    mreg[r * 4 + n] = Mb[moff[r] + kvn + n * 16 + c];
        }

        #pragma unroll
        for (int s8 = 0; s8 < 8; ++s8) {
            floatx4 o = accO[s8];
            o[0] *= corr[0]; o[1] *= corr[1]; o[2] *= corr[2]; o[3] *= corr[3];
            accO[s8] = o;
        }

        #pragma unroll
        for (int r = 0; r < 4; ++r) {
            int rl = 4 * g + r;
            #pragma unroll
            for (int n = 0; n < 4; ++n) {
                unsigned colb = (unsigned)((n * 16 + c) * 2) ^ (unsigned)((rl & 7) << 4);
                *(unsigned short*)(psw + rl * 128 + colb) = f2b(pv[n][r]);
            }
        }

        #pragma unroll
        for (int sub = 0; sub < 2; ++sub) {
            unsigned colb = (unsigned)(sub * 64 + g * 16) ^ (unsigned)((c & 7) << 4);
            short8 pf = *(const short8*)(psw + c * 128 + colb);
            #pragma unroll
            for (int s8 = 0; s8 < 8; ++s8) {
                short8 vf = *(const short8*)(VTp + (s8 * 16 + c) * 144 + sub * 64 + g * 16);
                accO[s8] = __builtin_amdgcn_mfma_f32_16x16x32_bf16(pf, vf, accO[s8], 0, 0, 0);
            }
        }

        if (step + 1 < NSTEP) {
            char* KHn = lds + (p ^ 1) * 16384;
            char* VTn = lds + 32768 + (p ^ 1) * 18432;
            #pragma unroll
            for (int i = 0; i < 8; ++i) {
                float4 kv = kreg[i];
                unsigned long long kp =
                      (unsigned long long)f2b(kv.x)
                    | ((unsigned long long)f2b(kv.y) << 16)
                    | ((unsigned long long)f2b(kv.z) << 32)
                    | ((unsigned long long)f2b(kv.w) << 48);
                *(unsigned long long*)(KHn + (i * 8 + rbase) * 256 + swk) = kp;
            }
            char* vbase = VTn + vd * 144 + vk0 * 2;
            #pragma unroll
            for (int i = 0; i < 4; ++i) {
                short8 pk;
                #pragma unroll
                for (int e = 0; e < 8; ++e) pk[e] = f2b(vreg[i * 8 + e]);
                *(short8*)(vbase + i * 16) = pk;
            }
            if (step + 2 < NSTEP) {
                const int kvn2 = kv0 + 2 * BKV;
                #pragma unroll
                for (int i = 0; i < 8; ++i)
                    kreg[i] = *(const float4*)(Kb + (size_t)(kvn2 + i * 8 + rbase) * DH + c4 * 4);
                #pragma unroll
                for (int j = 0; j < 32; ++j)
                    vreg[j] = Vb[(size_t)(kvn2 + vk0 + j) * DH + vd];
            }
        }
        __syncthreads();
    }

    float inv[4];
    #pragma unroll
    for (int r = 0; r < 4; ++r) inv[r] = (l_run[r] > 0.f) ? 1.f / l_run[r] : 0.f;
    float* Ob = O + ((size_t)(b * S_LEN + q0 + w * 16)) * DH;
    #pragma unroll
    for (int s8 = 0; s8 < 8; ++s8) {
        #pragma unroll
        for (int r = 0; r < 4; ++r) {
            Ob[(size_t)(4 * g + r) * DH + s8 * 16 + c] = accO[s8][r] * inv[r];
        }
    }
}

extern "C" void kernel_launch(void* const* d_in, const int* in_sizes, int n_in,
                              void* d_out, int out_size, void* d_ws, size_t ws_size,
                              hipStream_t stream) {
    const float* Q = (const float*)d_in[0];
    const float* K = (const float*)d_in[1];
    const float* V = (const float*)d_in[2];
    const int*   M = (const int*)d_in[3];
    float*       O = (float*)d_out;

    const size_t elems    = (size_t)16 * S_LEN * DH;
    const size_t kv_bytes = elems * sizeof(unsigned short);
    if (ws_size >= 2 * kv_bytes) {
        unsigned short* KFp = (unsigned short*)d_ws;
        unsigned short* VFp = (unsigned short*)d_ws + elems;
        kfrag_make<<<dim3(32, 16), dim3(256), 0, stream>>>(K, KFp);
        vfrag_make<<<dim3(S_LEN / 32, DH / 32, 16), dim3(256), 0, stream>>>(V, VFp);
        attn_fwd<<<dim3(S_LEN / BQ, 16), dim3(256), 0, stream>>>(Q, KFp, VFp, M, O);
    } else {
        attn_fwd_fb<<<dim3(S_LEN / 64, 16), dim3(256), 0, stream>>>(Q, K, V, M, O);
    }
}